// Round 1
// baseline (10214.252 us; speedup 1.0000x reference)
//
#include <hip/hip_runtime.h>
#include <math.h>

#define F 128
#define NH 8
#define HD 16

static inline int cdiv(int a, int b) { return (a + b - 1) / b; }

__device__ __forceinline__ float geluf(float x) {
    return 0.5f * x * (1.f + erff(x * 0.70710678118654752440f));
}

__device__ __forceinline__ void atomicMaxF(float* addr, float v) {
    if (v >= 0.f) atomicMax((int*)addr, __float_as_int(v));
    else          atomicMin((unsigned int*)addr, (unsigned int)__float_as_int(v));
}

__device__ __forceinline__ void atomAddF(float* p, float v) {
    __hip_atomic_fetch_add(p, v, __ATOMIC_RELAXED, __HIP_MEMORY_SCOPE_AGENT);
}

// Build fused relation weights:
//   Wfk[e][i][h*16+j] = sum_d Wk[l][s(e)][i][h*16+d] * arel[l][e][h][d][j]   (i<128)
//   row i==128 holds the fused bias: sum_d bk[l][s(e)][h*16+d] * arel[l][e][h][d][j]
// Same for Wfv with Wv/mrel/bv.
__global__ void build_fused(const float* __restrict__ Wk, const float* __restrict__ bk,
                            const float* __restrict__ Wv, const float* __restrict__ bv,
                            const float* __restrict__ arel, const float* __restrict__ mrel,
                            int layer, float* __restrict__ Wfk, float* __restrict__ Wfv) {
    const int total = 3 * 129 * 128;
    int idx = blockIdx.x * blockDim.x + threadIdx.x;
    if (idx >= 2 * total) return;
    int which = idx / total;          // 0 = k-path, 1 = v-path
    int rem = idx % total;
    int e = rem / (129 * 128);
    int rc = rem % (129 * 128);
    int i = rc / 128;                 // 0..128 (128 == bias row)
    int c = rc % 128;
    int h = c >> 4, j = c & 15;
    const int stab[3] = {0, 1, 0};    // source type per edge type
    int s = stab[e];
    const float* W  = which ? Wv : Wk;
    const float* bb = which ? bv : bk;
    const float* R  = which ? mrel : arel;
    const float* Wlt = W + (size_t)(layer * 2 + s) * F * F;
    const float* blt = bb + (size_t)(layer * 2 + s) * F;
    const float* Rm  = R + (size_t)((layer * 3 + e) * NH + h) * HD * HD;
    float sum = 0.f;
    if (i < 128) {
        #pragma unroll
        for (int d = 0; d < HD; ++d) sum += Wlt[i * F + h * HD + d] * Rm[d * HD + j];
    } else {
        #pragma unroll
        for (int d = 0; d < HD; ++d) sum += blt[h * HD + d] * Rm[d * HD + j];
    }
    float* dst = which ? Wfv : Wfk;
    dst[(size_t)e * 129 * 128 + (size_t)i * 128 + c] = sum;
}

// C[N,128] = A[N,128] @ W[128,128] + bias[128]
// MODE 0: plain.  MODE 1: A := gelu(A) on load; epilogue out = sg*o + (1-sg)*xres, optional relu.
template <int MODE>
__global__ __launch_bounds__(256) void gemm128(
    const float* __restrict__ A, const float* __restrict__ W,
    const float* __restrict__ bias, const float* __restrict__ xres,
    const float* __restrict__ skipp, float* __restrict__ C,
    int N, int do_relu) {
    __shared__ float Ws[128 * 128];
    __shared__ float As[64 * 132];   // +4 pad breaks 128-stride bank aliasing
    const int tid = threadIdx.x;
    const int row0 = blockIdx.x * 64;

    for (int i = tid * 4; i < 128 * 128; i += 1024)
        *(float4*)&Ws[i] = *(const float4*)&W[i];

    for (int i = tid * 4; i < 64 * 128; i += 1024) {
        int r = i >> 7, k = i & 127;
        int gr = row0 + r;
        float4 v = make_float4(0.f, 0.f, 0.f, 0.f);
        if (gr < N) v = *(const float4*)&A[(size_t)gr * F + k];
        if (MODE == 1) { v.x = geluf(v.x); v.y = geluf(v.y); v.z = geluf(v.z); v.w = geluf(v.w); }
        *(float4*)&As[r * 132 + k] = v;
    }
    __syncthreads();

    const int rq = (tid >> 4) * 4;     // 4 rows per thread
    const int c0 = (tid & 15) * 8;     // 8 cols per thread
    float acc[4][8];
    #pragma unroll
    for (int r = 0; r < 4; ++r)
        #pragma unroll
        for (int c = 0; c < 8; ++c) acc[r][c] = 0.f;

    for (int k = 0; k < 128; k += 4) {
        float a[4][4];
        #pragma unroll
        for (int r = 0; r < 4; ++r) {
            float4 t4 = *(float4*)&As[(rq + r) * 132 + k];
            a[r][0] = t4.x; a[r][1] = t4.y; a[r][2] = t4.z; a[r][3] = t4.w;
        }
        #pragma unroll
        for (int kk = 0; kk < 4; ++kk) {
            float4 w0 = *(float4*)&Ws[(k + kk) * 128 + c0];
            float4 w1 = *(float4*)&Ws[(k + kk) * 128 + c0 + 4];
            float w[8] = {w0.x, w0.y, w0.z, w0.w, w1.x, w1.y, w1.z, w1.w};
            #pragma unroll
            for (int r = 0; r < 4; ++r)
                #pragma unroll
                for (int c = 0; c < 8; ++c)
                    acc[r][c] = fmaf(a[r][kk], w[c], acc[r][c]);
        }
    }

    float bl[8];
    #pragma unroll
    for (int c = 0; c < 8; ++c) bl[c] = bias[c0 + c];
    float sg = 0.f;
    if (MODE == 1) sg = 1.f / (1.f + expf(-skipp[0]));

    #pragma unroll
    for (int r = 0; r < 4; ++r) {
        int gr = row0 + rq + r;
        if (gr >= N) continue;
        float o[8];
        #pragma unroll
        for (int c = 0; c < 8; ++c) {
            float v = acc[r][c] + bl[c];
            if (MODE == 1) {
                float xr = xres[(size_t)gr * F + c0 + c];
                v = sg * v + (1.f - sg) * xr;
                if (do_relu) v = fmaxf(v, 0.f);
            }
            o[c] = v;
        }
        *(float4*)&C[(size_t)gr * F + c0]     = make_float4(o[0], o[1], o[2], o[3]);
        *(float4*)&C[(size_t)gr * F + c0 + 4] = make_float4(o[4], o[5], o[6], o[7]);
    }
}

__global__ void init_md(float* __restrict__ amax, float* __restrict__ den, int n) {
    int i = blockIdx.x * blockDim.x + threadIdx.x;
    if (i < n) { amax[i] = -INFINITY; den[i] = 0.f; }
}

__global__ void edge_alpha(const float* __restrict__ q, const float* __restrict__ krel,
                           const int* __restrict__ ei, const float* __restrict__ prel,
                           float* __restrict__ alpha, float* __restrict__ amax, int E) {
    int idx = blockIdx.x * blockDim.x + threadIdx.x;
    if (idx >= E * NH) return;
    int i = idx >> 3, h = idx & 7;
    int src = ei[i], dst = ei[E + i];
    const float* qp = q + (size_t)dst * F + h * HD;
    const float* kp = krel + (size_t)src * F + h * HD;
    float s = 0.f;
    #pragma unroll
    for (int d = 0; d < HD; d += 4) {
        float4 a = *(const float4*)(qp + d);
        float4 b = *(const float4*)(kp + d);
        s += a.x * b.x + a.y * b.y + a.z * b.z + a.w * b.w;
    }
    s *= prel[h] * 0.25f;   // /sqrt(16)
    alpha[idx] = s;
    atomicMaxF(amax + (size_t)dst * NH + h, s);
}

__global__ void edge_ex(float* __restrict__ alpha, const float* __restrict__ amax,
                        float* __restrict__ den, const int* __restrict__ ei, int E) {
    int idx = blockIdx.x * blockDim.x + threadIdx.x;
    if (idx >= E * NH) return;
    int i = idx >> 3, h = idx & 7;
    int dst = ei[E + i];
    float ex = expf(alpha[idx] - amax[(size_t)dst * NH + h]);
    alpha[idx] = ex;
    atomAddF(den + (size_t)dst * NH + h, ex);
}

__global__ void edge_agg(const float* __restrict__ alpha, const float* __restrict__ den,
                         const float* __restrict__ vrel, const int* __restrict__ ei,
                         float* __restrict__ agg, int E) {
    int idx = blockIdx.x * blockDim.x + threadIdx.x;
    if (idx >= E * NH) return;
    int i = idx >> 3, h = idx & 7;
    int src = ei[i], dst = ei[E + i];
    float w = alpha[idx] / (den[(size_t)dst * NH + h] + 1e-16f);
    const float* vp = vrel + (size_t)src * F + h * HD;
    float* ap = agg + (size_t)dst * F + h * HD;
    #pragma unroll
    for (int d = 0; d < HD; ++d) atomAddF(ap + d, vp[d] * w);
}

extern "C" void kernel_launch(void* const* d_in, const int* in_sizes, int n_in,
                              void* d_out, int out_size, void* d_ws, size_t ws_size,
                              hipStream_t stream) {
    const float* xa   = (const float*)d_in[0];
    const float* xb   = (const float*)d_in[1];
    const int* ei_ab  = (const int*)d_in[2];
    const int* ei_ba  = (const int*)d_in[3];
    const int* ei_aa  = (const int*)d_in[4];
    const float* Wk   = (const float*)d_in[5];
    const float* bk   = (const float*)d_in[6];
    const float* Wq   = (const float*)d_in[7];
    const float* bq   = (const float*)d_in[8];
    const float* Wv   = (const float*)d_in[9];
    const float* bv   = (const float*)d_in[10];
    const float* Wa   = (const float*)d_in[11];
    const float* ba   = (const float*)d_in[12];
    const float* skip = (const float*)d_in[13];
    const float* arel = (const float*)d_in[14];
    const float* mrel = (const float*)d_in[15];
    const float* prel = (const float*)d_in[16];

    const int NA = in_sizes[0] / F;
    const int NB = in_sizes[1] / F;
    const int Es[3] = {in_sizes[2] / 2, in_sizes[3] / 2, in_sizes[4] / 2};
    const int Nmax = NA > NB ? NA : NB;
    int Emax = Es[0];
    for (int e = 1; e < 3; ++e) if (Es[e] > Emax) Emax = Es[e];

    float* ws = (float*)d_ws;
    size_t o = 0;
    float* q0   = ws + o; o += (size_t)NA * F;
    float* q1   = ws + o; o += (size_t)NB * F;
    float* krel = ws + o; o += (size_t)Nmax * F;
    float* vrel = ws + o; o += (size_t)Nmax * F;
    float* agg0 = ws + o; o += (size_t)NA * F;
    float* agg1 = ws + o; o += (size_t)NB * F;
    float* x1a  = ws + o; o += (size_t)NA * F;
    float* x1b  = ws + o; o += (size_t)NB * F;
    float* alpha= ws + o; o += (size_t)Emax * NH;
    float* amax = ws + o; o += (size_t)Nmax * NH;
    float* den  = ws + o; o += (size_t)Nmax * NH;
    float* Wfk  = ws + o; o += (size_t)3 * 129 * 128;
    float* Wfv  = ws + o; o += (size_t)3 * 129 * 128;

    float* outA = (float*)d_out;
    float* outB = (float*)d_out + (size_t)NA * F;

    for (int l = 0; l < 2; ++l) {
        const float* x0 = l ? x1a : xa;
        const float* x1 = l ? x1b : xb;

        {   // fused relation weights for this layer
            int total = 2 * 3 * 129 * 128;
            build_fused<<<cdiv(total, 256), 256, 0, stream>>>(Wk, bk, Wv, bv, arel, mrel, l, Wfk, Wfv);
        }

        // Q projections
        gemm128<0><<<cdiv(NA, 64), 256, 0, stream>>>(x0, Wq + (size_t)(l * 2 + 0) * F * F,
            bq + (size_t)(l * 2 + 0) * F, nullptr, nullptr, q0, NA, 0);
        gemm128<0><<<cdiv(NB, 64), 256, 0, stream>>>(x1, Wq + (size_t)(l * 2 + 1) * F * F,
            bq + (size_t)(l * 2 + 1) * F, nullptr, nullptr, q1, NB, 0);

        hipMemsetAsync(agg0, 0, (size_t)NA * F * sizeof(float), stream);
        hipMemsetAsync(agg1, 0, (size_t)NB * F * sizeof(float), stream);

        for (int e = 0; e < 3; ++e) {
            const int* ei = e == 0 ? ei_ab : (e == 1 ? ei_ba : ei_aa);
            int Ee = Es[e];
            const float* xs = (e == 1) ? x1 : x0;
            int Ns = (e == 1) ? NB : NA;
            int Nd = (e == 0) ? NB : NA;
            const float* qd = (e == 0) ? q1 : q0;
            float* aggd = (e == 0) ? agg1 : agg0;

            const float* Wke = Wfk + (size_t)e * 129 * 128;
            const float* Wve = Wfv + (size_t)e * 129 * 128;
            gemm128<0><<<cdiv(Ns, 64), 256, 0, stream>>>(xs, Wke, Wke + 128 * 128,
                nullptr, nullptr, krel, Ns, 0);
            gemm128<0><<<cdiv(Ns, 64), 256, 0, stream>>>(xs, Wve, Wve + 128 * 128,
                nullptr, nullptr, vrel, Ns, 0);

            init_md<<<cdiv(Nd * NH, 256), 256, 0, stream>>>(amax, den, Nd * NH);
            edge_alpha<<<cdiv(Ee * NH, 256), 256, 0, stream>>>(qd, krel, ei,
                prel + (size_t)(l * 3 + e) * NH, alpha, amax, Ee);
            edge_ex<<<cdiv(Ee * NH, 256), 256, 0, stream>>>(alpha, amax, den, ei, Ee);
            edge_agg<<<cdiv(Ee * NH, 256), 256, 0, stream>>>(alpha, den, vrel, ei, aggd, Ee);
        }

        float* o0 = l ? outA : x1a;
        float* o1 = l ? outB : x1b;
        gemm128<1><<<cdiv(NA, 64), 256, 0, stream>>>(agg0, Wa + (size_t)(l * 2 + 0) * F * F,
            ba + (size_t)(l * 2 + 0) * F, x0, skip + l * 2 + 0, o0, NA, l == 0 ? 1 : 0);
        gemm128<1><<<cdiv(NB, 64), 256, 0, stream>>>(agg1, Wa + (size_t)(l * 2 + 1) * F * F,
            ba + (size_t)(l * 2 + 1) * F, x1, skip + l * 2 + 1, o1, NB, l == 0 ? 1 : 0);
    }
}

// Round 2
// 1973.932 us; speedup vs baseline: 5.1746x; 5.1746x over previous
//
#include <hip/hip_runtime.h>
#include <math.h>

#define F 128
#define NH 8
#define HD 16

static inline int cdiv(int a, int b) { return (a + b - 1) / b; }

__device__ __forceinline__ float geluf(float x) {
    return 0.5f * x * (1.f + erff(x * 0.70710678118654752440f));
}

// Build fused relation weights:
//   Wfk[e][i][h*16+j] = sum_d Wk[l][s(e)][i][h*16+d] * arel[l][e][h][d][j]   (i<128)
//   row i==128 holds the fused bias.
__global__ void build_fused(const float* __restrict__ Wk, const float* __restrict__ bk,
                            const float* __restrict__ Wv, const float* __restrict__ bv,
                            const float* __restrict__ arel, const float* __restrict__ mrel,
                            int layer, float* __restrict__ Wfk, float* __restrict__ Wfv) {
    const int total = 3 * 129 * 128;
    int idx = blockIdx.x * blockDim.x + threadIdx.x;
    if (idx >= 2 * total) return;
    int which = idx / total;          // 0 = k-path, 1 = v-path
    int rem = idx % total;
    int e = rem / (129 * 128);
    int rc = rem % (129 * 128);
    int i = rc / 128;                 // 0..128 (128 == bias row)
    int c = rc % 128;
    int h = c >> 4, j = c & 15;
    const int stab[3] = {0, 1, 0};    // source type per edge type
    int s = stab[e];
    const float* W  = which ? Wv : Wk;
    const float* bb = which ? bv : bk;
    const float* R  = which ? mrel : arel;
    const float* Wlt = W + (size_t)(layer * 2 + s) * F * F;
    const float* blt = bb + (size_t)(layer * 2 + s) * F;
    const float* Rm  = R + (size_t)((layer * 3 + e) * NH + h) * HD * HD;
    float sum = 0.f;
    if (i < 128) {
        #pragma unroll
        for (int d = 0; d < HD; ++d) sum += Wlt[i * F + h * HD + d] * Rm[d * HD + j];
    } else {
        #pragma unroll
        for (int d = 0; d < HD; ++d) sum += blt[h * HD + d] * Rm[d * HD + j];
    }
    float* dst = which ? Wfv : Wfk;
    dst[(size_t)e * 129 * 128 + (size_t)i * 128 + c] = sum;
}

// C[N,128] = A[N,128] @ W[128,128] + bias[128]
// MODE 0: plain.  MODE 1: A := gelu(A) on load; epilogue out = sg*o + (1-sg)*xres, optional relu.
template <int MODE>
__global__ __launch_bounds__(256) void gemm128(
    const float* __restrict__ A, const float* __restrict__ W,
    const float* __restrict__ bias, const float* __restrict__ xres,
    const float* __restrict__ skipp, float* __restrict__ C,
    int N, int do_relu) {
    __shared__ float Ws[128 * 128];
    __shared__ float As[64 * 132];
    const int tid = threadIdx.x;
    const int row0 = blockIdx.x * 64;

    for (int i = tid * 4; i < 128 * 128; i += 1024)
        *(float4*)&Ws[i] = *(const float4*)&W[i];

    for (int i = tid * 4; i < 64 * 128; i += 1024) {
        int r = i >> 7, k = i & 127;
        int gr = row0 + r;
        float4 v = make_float4(0.f, 0.f, 0.f, 0.f);
        if (gr < N) v = *(const float4*)&A[(size_t)gr * F + k];
        if (MODE == 1) { v.x = geluf(v.x); v.y = geluf(v.y); v.z = geluf(v.z); v.w = geluf(v.w); }
        *(float4*)&As[r * 132 + k] = v;
    }
    __syncthreads();

    const int rq = (tid >> 4) * 4;
    const int c0 = (tid & 15) * 8;
    float acc[4][8];
    #pragma unroll
    for (int r = 0; r < 4; ++r)
        #pragma unroll
        for (int c = 0; c < 8; ++c) acc[r][c] = 0.f;

    for (int k = 0; k < 128; k += 4) {
        float a[4][4];
        #pragma unroll
        for (int r = 0; r < 4; ++r) {
            float4 t4 = *(float4*)&As[(rq + r) * 132 + k];
            a[r][0] = t4.x; a[r][1] = t4.y; a[r][2] = t4.z; a[r][3] = t4.w;
        }
        #pragma unroll
        for (int kk = 0; kk < 4; ++kk) {
            float4 w0 = *(float4*)&Ws[(k + kk) * 128 + c0];
            float4 w1 = *(float4*)&Ws[(k + kk) * 128 + c0 + 4];
            float w[8] = {w0.x, w0.y, w0.z, w0.w, w1.x, w1.y, w1.z, w1.w};
            #pragma unroll
            for (int r = 0; r < 4; ++r)
                #pragma unroll
                for (int c = 0; c < 8; ++c)
                    acc[r][c] = fmaf(a[r][kk], w[c], acc[r][c]);
        }
    }

    float bl[8];
    #pragma unroll
    for (int c = 0; c < 8; ++c) bl[c] = bias[c0 + c];
    float sg = 0.f;
    if (MODE == 1) sg = 1.f / (1.f + expf(-skipp[0]));

    #pragma unroll
    for (int r = 0; r < 4; ++r) {
        int gr = row0 + rq + r;
        if (gr >= N) continue;
        float o[8];
        #pragma unroll
        for (int c = 0; c < 8; ++c) {
            float v = acc[r][c] + bl[c];
            if (MODE == 1) {
                float xr = xres[(size_t)gr * F + c0 + c];
                v = sg * v + (1.f - sg) * xr;
                if (do_relu) v = fmaxf(v, 0.f);
            }
            o[c] = v;
        }
        *(float4*)&C[(size_t)gr * F + c0]     = make_float4(o[0], o[1], o[2], o[3]);
        *(float4*)&C[(size_t)gr * F + c0 + 4] = make_float4(o[4], o[5], o[6], o[7]);
    }
}

// ---------------- CSR build (once per edge type; reused across layers) ------

__global__ void hist_kernel(const int* __restrict__ dst, int E, int* __restrict__ cnt) {
    int i = blockIdx.x * blockDim.x + threadIdx.x;
    if (i < E) atomicAdd(&cnt[dst[i]], 1);
}

// single-block exclusive scan: off[0..n] (off[n]=total), woff copy for scatter
__global__ __launch_bounds__(1024) void exscan_kernel(const int* __restrict__ cnt,
                                                      int* __restrict__ off,
                                                      int* __restrict__ woff, int n) {
    __shared__ int lds[1024];
    __shared__ int carry_s;
    const int tid = threadIdx.x;
    if (tid == 0) carry_s = 0;
    __syncthreads();
    for (int base = 0; base < n; base += 1024) {
        int i = base + tid;
        int v = (i < n) ? cnt[i] : 0;
        lds[tid] = v;
        __syncthreads();
        #pragma unroll
        for (int s = 1; s < 1024; s <<= 1) {
            int t = (tid >= s) ? lds[tid - s] : 0;
            __syncthreads();
            lds[tid] += t;
            __syncthreads();
        }
        int total = lds[1023];
        int excl = lds[tid] - v + carry_s;
        if (i < n) { off[i] = excl; woff[i] = excl; }
        __syncthreads();
        if (tid == 0) carry_s += total;
        __syncthreads();
    }
    if (tid == 0) off[n] = carry_s;
}

__global__ void scatter_kernel(const int* __restrict__ src, const int* __restrict__ dst,
                               int E, int* __restrict__ woff, int* __restrict__ csr_src) {
    int i = blockIdx.x * blockDim.x + threadIdx.x;
    if (i < E) {
        int p = atomicAdd(&woff[dst[i]], 1);
        csr_src[p] = src[i];
    }
}

// ---------------- fused segment attention: max+softmax+weighted agg ---------
// 128 threads per dst node (8 heads x 16 dims), 2 dst per 256-block.
__global__ __launch_bounds__(256) void seg_attn(
    const float* __restrict__ q, const float* __restrict__ krel,
    const float* __restrict__ vrel, const int* __restrict__ csr_off,
    const int* __restrict__ csr_src, const float* __restrict__ prel,
    float* __restrict__ agg, int Nd) {
    int dst = blockIdx.x * 2 + (threadIdx.x >> 7);
    if (dst >= Nd) return;
    int t = threadIdx.x & 127;
    int h = t >> 4;
    float qv = q[(size_t)dst * F + t];
    float pr = prel[h] * 0.25f;           // 1/sqrt(16)
    int e0 = csr_off[dst], e1 = csr_off[dst + 1];
    float m = -INFINITY, den = 0.f, acc = 0.f;
    for (int j = e0; j < e1; ++j) {
        int src = csr_src[j];
        float kv = krel[(size_t)src * F + t];
        float vv = vrel[(size_t)src * F + t];
        float p = qv * kv;
        p += __shfl_xor(p, 8, 16);
        p += __shfl_xor(p, 4, 16);
        p += __shfl_xor(p, 2, 16);
        p += __shfl_xor(p, 1, 16);
        float alpha = p * pr;
        float nm = fmaxf(m, alpha);
        float corr = __expf(m - nm);      // first iter: exp(-inf)=0
        float ex = __expf(alpha - nm);
        den = den * corr + ex;
        acc = acc * corr + ex * vv;
        m = nm;
    }
    agg[(size_t)dst * F + t] += acc / (den + 1e-16f);
}

extern "C" void kernel_launch(void* const* d_in, const int* in_sizes, int n_in,
                              void* d_out, int out_size, void* d_ws, size_t ws_size,
                              hipStream_t stream) {
    const float* xa   = (const float*)d_in[0];
    const float* xb   = (const float*)d_in[1];
    const int* ei_ab  = (const int*)d_in[2];
    const int* ei_ba  = (const int*)d_in[3];
    const int* ei_aa  = (const int*)d_in[4];
    const float* Wk   = (const float*)d_in[5];
    const float* bk   = (const float*)d_in[6];
    const float* Wq   = (const float*)d_in[7];
    const float* bq   = (const float*)d_in[8];
    const float* Wv   = (const float*)d_in[9];
    const float* bv   = (const float*)d_in[10];
    const float* Wa   = (const float*)d_in[11];
    const float* ba   = (const float*)d_in[12];
    const float* skip = (const float*)d_in[13];
    const float* arel = (const float*)d_in[14];
    const float* mrel = (const float*)d_in[15];
    const float* prel = (const float*)d_in[16];

    const int NA = in_sizes[0] / F;
    const int NB = in_sizes[1] / F;
    const int Es[3] = {in_sizes[2] / 2, in_sizes[3] / 2, in_sizes[4] / 2};
    const int Nmax = NA > NB ? NA : NB;

    float* ws = (float*)d_ws;
    size_t o = 0;
    float* q0   = ws + o; o += (size_t)NA * F;
    float* q1   = ws + o; o += (size_t)NB * F;
    float* krel = ws + o; o += (size_t)Nmax * F;
    float* vrel = ws + o; o += (size_t)Nmax * F;
    float* agg0 = ws + o; o += (size_t)NA * F;
    float* agg1 = ws + o; o += (size_t)NB * F;
    float* x1a  = ws + o; o += (size_t)NA * F;
    float* x1b  = ws + o; o += (size_t)NB * F;
    float* Wfk  = ws + o; o += (size_t)3 * 129 * 128;
    float* Wfv  = ws + o; o += (size_t)3 * 129 * 128;
    // CSR (ints)
    int* iws = (int*)(ws + o);
    size_t io = 0;
    int* cnt = iws + io; io += Nmax;
    int* csr_off[3]; int* csr_woff[3]; int* csr_src[3];
    for (int e = 0; e < 3; ++e) {
        csr_off[e]  = iws + io; io += Nmax + 1;
        csr_woff[e] = iws + io; io += Nmax;
        csr_src[e]  = iws + io; io += Es[e];
    }

    float* outA = (float*)d_out;
    float* outB = (float*)d_out + (size_t)NA * F;

    const int* eis[3] = {ei_ab, ei_ba, ei_aa};
    const int Nds[3] = {NB, NA, NA};

    // ---- build CSR once per edge type (edge lists shared by both layers) ----
    for (int e = 0; e < 3; ++e) {
        int Ee = Es[e], Nd = Nds[e];
        const int* dstp = eis[e] + Ee;
        hipMemsetAsync(cnt, 0, (size_t)Nd * sizeof(int), stream);
        hist_kernel<<<cdiv(Ee, 256), 256, 0, stream>>>(dstp, Ee, cnt);
        exscan_kernel<<<1, 1024, 0, stream>>>(cnt, csr_off[e], csr_woff[e], Nd);
        scatter_kernel<<<cdiv(Ee, 256), 256, 0, stream>>>(eis[e], dstp, Ee, csr_woff[e], csr_src[e]);
    }

    for (int l = 0; l < 2; ++l) {
        const float* x0 = l ? x1a : xa;
        const float* x1 = l ? x1b : xb;

        {
            int total = 2 * 3 * 129 * 128;
            build_fused<<<cdiv(total, 256), 256, 0, stream>>>(Wk, bk, Wv, bv, arel, mrel, l, Wfk, Wfv);
        }

        gemm128<0><<<cdiv(NA, 64), 256, 0, stream>>>(x0, Wq + (size_t)(l * 2 + 0) * F * F,
            bq + (size_t)(l * 2 + 0) * F, nullptr, nullptr, q0, NA, 0);
        gemm128<0><<<cdiv(NB, 64), 256, 0, stream>>>(x1, Wq + (size_t)(l * 2 + 1) * F * F,
            bq + (size_t)(l * 2 + 1) * F, nullptr, nullptr, q1, NB, 0);

        hipMemsetAsync(agg0, 0, (size_t)NA * F * sizeof(float), stream);
        hipMemsetAsync(agg1, 0, (size_t)NB * F * sizeof(float), stream);

        for (int e = 0; e < 3; ++e) {
            int Ee = Es[e];
            const float* xs = (e == 1) ? x1 : x0;
            int Ns = (e == 1) ? NB : NA;
            int Nd = Nds[e];
            const float* qd = (e == 0) ? q1 : q0;
            float* aggd = (e == 0) ? agg1 : agg0;

            const float* Wke = Wfk + (size_t)e * 129 * 128;
            const float* Wve = Wfv + (size_t)e * 129 * 128;
            gemm128<0><<<cdiv(Ns, 64), 256, 0, stream>>>(xs, Wke, Wke + 128 * 128,
                nullptr, nullptr, krel, Ns, 0);
            gemm128<0><<<cdiv(Ns, 64), 256, 0, stream>>>(xs, Wve, Wve + 128 * 128,
                nullptr, nullptr, vrel, Ns, 0);

            seg_attn<<<cdiv(Nd, 2), 256, 0, stream>>>(qd, krel, vrel,
                csr_off[e], csr_src[e], prel + (size_t)(l * 3 + e) * NH, aggd, Nd);
        }

        float* o0 = l ? outA : x1a;
        float* o1 = l ? outB : x1b;
        gemm128<1><<<cdiv(NA, 64), 256, 0, stream>>>(agg0, Wa + (size_t)(l * 2 + 0) * F * F,
            ba + (size_t)(l * 2 + 0) * F, x0, skip + l * 2 + 0, o0, NA, l == 0 ? 1 : 0);
        gemm128<1><<<cdiv(NB, 64), 256, 0, stream>>>(agg1, Wa + (size_t)(l * 2 + 1) * F * F,
            ba + (size_t)(l * 2 + 1) * F, x1, skip + l * 2 + 1, o1, NB, l == 0 ? 1 : 0);
    }
}

// Round 3
// 962.952 us; speedup vs baseline: 10.6072x; 2.0499x over previous
//
#include <hip/hip_runtime.h>
#include <hip/hip_bf16.h>
#include <math.h>

#define F 128
#define NH 8
#define HD 16

static inline int cdiv(int a, int b) { return (a + b - 1) / b; }

typedef __attribute__((ext_vector_type(8))) short bf16x8;
typedef __attribute__((ext_vector_type(4))) float f32x4;

__device__ __forceinline__ float geluf(float x) {
    return 0.5f * x * (1.f + erff(x * 0.70710678118654752440f));
}

__device__ __forceinline__ short f2bf(float f) {
    __hip_bfloat16 h = __float2bfloat16(f);
    return *reinterpret_cast<short*>(&h);
}

// ---- weight prep: bf16 transposed [n][k] ----------------------------------

// Wq/Wa for this layer -> 4 slots of 128x128 bf16 (n-major)
__global__ void conv_wt4(const float* __restrict__ Wq, const float* __restrict__ Wa,
                         int layer, short* __restrict__ out) {
    int idx = blockIdx.x * blockDim.x + threadIdx.x;
    if (idx >= 4 * 16384) return;
    int which = idx >> 14;           // 0:q0 1:q1 2:a0 3:a1
    int rem = idx & 16383;
    int n = rem >> 7, k = rem & 127;
    const float* W = (which < 2 ? Wq : Wa) + (size_t)(layer * 2 + (which & 1)) * 16384;
    out[(size_t)which * 16384 + n * 128 + k] = f2bf(W[k * 128 + n]);
}

// Fused relation weights, bf16 transposed + f32 fused bias:
//   Wtk[e][n][k] = sum_d Wk[l][s(e)][k][h*16+d] * arel[l][e][h][d][j],  n=h*16+j
//   bfk[e][n]    = sum_d bk[l][s(e)][h*16+d]    * arel[l][e][h][d][j]
__global__ void build_fused_bf(const float* __restrict__ Wk, const float* __restrict__ bk,
                               const float* __restrict__ Wv, const float* __restrict__ bv,
                               const float* __restrict__ arel, const float* __restrict__ mrel,
                               int layer, short* __restrict__ Wtk, short* __restrict__ Wtv,
                               float* __restrict__ bfk, float* __restrict__ bfv) {
    const int WTOT = 3 * 128 * 128;
    int idx = blockIdx.x * blockDim.x + threadIdx.x;
    const int stab[3] = {0, 1, 0};
    if (idx < 2 * WTOT) {
        int which = idx / WTOT, rem = idx % WTOT;
        int e = rem >> 14;
        int n = (rem >> 7) & 127;
        int k = rem & 127;
        int h = n >> 4, j = n & 15;
        int s = stab[e];
        const float* W = (which ? Wv : Wk) + (size_t)(layer * 2 + s) * 16384;
        const float* R = (which ? mrel : arel) + (size_t)((layer * 3 + e) * NH + h) * 256;
        float sum = 0.f;
        #pragma unroll
        for (int d = 0; d < HD; ++d) sum += W[k * 128 + h * 16 + d] * R[d * 16 + j];
        (which ? Wtv : Wtk)[(size_t)e * 16384 + n * 128 + k] = f2bf(sum);
    } else {
        int r = idx - 2 * WTOT;
        if (r < 2 * 3 * 128) {
            int which = r / 384, rem = r % 384;
            int e = rem >> 7, n = rem & 127;
            int h = n >> 4, j = n & 15, s = stab[e];
            const float* bb = (which ? bv : bk) + (size_t)(layer * 2 + s) * 128;
            const float* R = (which ? mrel : arel) + (size_t)((layer * 3 + e) * NH + h) * 256;
            float sum = 0.f;
            #pragma unroll
            for (int d = 0; d < HD; ++d) sum += bb[h * 16 + d] * R[d * 16 + j];
            (which ? bfv : bfk)[e * 128 + n] = sum;
        }
    }
}

// ---- bf16 MFMA GEMM: C[N,128] = A[N,128] @ W + bias -----------------------
// Wt is bf16 [n][k] (transposed). MODE 0: plain. MODE 1: gelu(A) on load;
// epilogue out = sg*o + (1-sg)*xres, optional relu.
template <int MODE>
__global__ __launch_bounds__(256) void gemm_mfma(
    const float* __restrict__ A, const short* __restrict__ Wt,
    const float* __restrict__ bias, const float* __restrict__ xres,
    const float* __restrict__ skipp, float* __restrict__ C, int N, int do_relu) {
    __shared__ short Ws[128 * 136];   // +8 bf16 pad: row stride 272B -> banks rotate
    __shared__ short As[64 * 136];
    const int tid = threadIdx.x;
    const int row0 = blockIdx.x * 64;

    #pragma unroll
    for (int it = 0; it < 8; ++it) {
        int chunk = tid + it * 256;               // 2048 x 8 bf16
        int r = chunk >> 4, c8 = (chunk & 15) * 8;
        *(int4*)&Ws[r * 136 + c8] = *(const int4*)&Wt[r * 128 + c8];
    }
    #pragma unroll
    for (int it = 0; it < 4; ++it) {
        int chunk = tid + it * 256;               // 1024 x 8 f32->bf16
        int r = chunk >> 4, c8 = (chunk & 15) * 8;
        int gr = row0 + r;
        float v[8] = {0.f, 0.f, 0.f, 0.f, 0.f, 0.f, 0.f, 0.f};
        if (gr < N) {
            float4 v0 = *(const float4*)&A[(size_t)gr * F + c8];
            float4 v1 = *(const float4*)&A[(size_t)gr * F + c8 + 4];
            v[0] = v0.x; v[1] = v0.y; v[2] = v0.z; v[3] = v0.w;
            v[4] = v1.x; v[5] = v1.y; v[6] = v1.z; v[7] = v1.w;
        }
        bf16x8 s;
        #pragma unroll
        for (int u = 0; u < 8; ++u) s[u] = f2bf(MODE == 1 ? geluf(v[u]) : v[u]);
        *(bf16x8*)&As[r * 136 + c8] = s;
    }
    __syncthreads();

    const int wave = tid >> 6;
    const int lane = tid & 63;
    const int m16 = lane & 15;        // A-row / B-col / D-col within 16-tile
    const int kg = lane >> 4;         // k-group
    const int arow = wave * 16 + m16;

    f32x4 acc[8] = {};
    #pragma unroll
    for (int k0 = 0; k0 < 128; k0 += 32) {
        bf16x8 a = *(const bf16x8*)&As[arow * 136 + k0 + kg * 8];
        #pragma unroll
        for (int nt = 0; nt < 8; ++nt) {
            bf16x8 b = *(const bf16x8*)&Ws[(nt * 16 + m16) * 136 + k0 + kg * 8];
            acc[nt] = __builtin_amdgcn_mfma_f32_16x16x32_bf16(a, b, acc[nt], 0, 0, 0);
        }
    }

    float sg = (MODE == 1) ? 1.f / (1.f + expf(-skipp[0])) : 0.f;
    #pragma unroll
    for (int nt = 0; nt < 8; ++nt) {
        int n = nt * 16 + m16;
        float bl = bias[n];
        #pragma unroll
        for (int r = 0; r < 4; ++r) {
            int gr = row0 + wave * 16 + kg * 4 + r;   // D: row=(lane>>4)*4+reg
            if (gr >= N) continue;
            float v = acc[nt][r] + bl;
            if (MODE == 1) {
                float xr = xres[(size_t)gr * F + n];
                v = sg * v + (1.f - sg) * xr;
                if (do_relu) v = fmaxf(v, 0.f);
            }
            C[(size_t)gr * F + n] = v;
        }
    }
}

// ---------------- CSR build (two-level scan, no serial bottleneck) ----------

__global__ void hist_kernel(const int* __restrict__ dst, int E, int* __restrict__ cnt) {
    int i = blockIdx.x * blockDim.x + threadIdx.x;
    if (i < E) atomicAdd(&cnt[dst[i]], 1);
}

__global__ void scan1(const int* __restrict__ cnt, int n, int* __restrict__ off,
                      int* __restrict__ bsum) {
    __shared__ int lds[256];
    int tid = threadIdx.x, i = blockIdx.x * 256 + tid;
    int v = (i < n) ? cnt[i] : 0;
    lds[tid] = v;
    __syncthreads();
    #pragma unroll
    for (int s = 1; s < 256; s <<= 1) {
        int t = (tid >= s) ? lds[tid - s] : 0;
        __syncthreads();
        lds[tid] += t;
        __syncthreads();
    }
    if (i < n) off[i] = lds[tid] - v;
    if (tid == 255) bsum[blockIdx.x] = lds[255];
}

__global__ __launch_bounds__(1024) void scan2(int* __restrict__ bsum, int nb,
                                              int* __restrict__ off_n) {
    __shared__ int lds[1024];
    int tid = threadIdx.x;
    int v = (tid < nb) ? bsum[tid] : 0;
    lds[tid] = v;
    __syncthreads();
    #pragma unroll
    for (int s = 1; s < 1024; s <<= 1) {
        int t = (tid >= s) ? lds[tid - s] : 0;
        __syncthreads();
        lds[tid] += t;
        __syncthreads();
    }
    if (tid < nb) bsum[tid] = lds[tid] - v;
    if (tid == 1023) *off_n = lds[1023];
}

__global__ void scan3(int* __restrict__ off, int* __restrict__ woff,
                      const int* __restrict__ bsum, int n) {
    int i = blockIdx.x * 256 + threadIdx.x;
    if (i < n) {
        int v = off[i] + bsum[blockIdx.x];
        off[i] = v;
        woff[i] = v;
    }
}

__global__ void scatter_kernel(const int* __restrict__ src, const int* __restrict__ dst,
                               int E, int* __restrict__ woff, int* __restrict__ csr_src) {
    int i = blockIdx.x * blockDim.x + threadIdx.x;
    if (i < E) {
        int p = atomicAdd(&woff[dst[i]], 1);
        csr_src[p] = src[i];
    }
}

// ---------------- fused segment attention ----------------------------------
__global__ __launch_bounds__(256) void seg_attn(
    const float* __restrict__ q, const float* __restrict__ krel,
    const float* __restrict__ vrel, const int* __restrict__ csr_off,
    const int* __restrict__ csr_src, const float* __restrict__ prel,
    float* __restrict__ agg, int Nd) {
    int dst = blockIdx.x * 2 + (threadIdx.x >> 7);
    if (dst >= Nd) return;
    int t = threadIdx.x & 127;
    int h = t >> 4;
    float qv = q[(size_t)dst * F + t];
    float pr = prel[h] * 0.25f;
    int e0 = csr_off[dst], e1 = csr_off[dst + 1];
    float m = -INFINITY, den = 0.f, acc = 0.f;
    for (int j = e0; j < e1; ++j) {
        int src = csr_src[j];
        float kv = krel[(size_t)src * F + t];
        float vv = vrel[(size_t)src * F + t];
        float p = qv * kv;
        p += __shfl_xor(p, 8, 16);
        p += __shfl_xor(p, 4, 16);
        p += __shfl_xor(p, 2, 16);
        p += __shfl_xor(p, 1, 16);
        float alpha = p * pr;
        float nm = fmaxf(m, alpha);
        float corr = __expf(m - nm);
        float ex = __expf(alpha - nm);
        den = den * corr + ex;
        acc = acc * corr + ex * vv;
        m = nm;
    }
    agg[(size_t)dst * F + t] += acc / (den + 1e-16f);
}

extern "C" void kernel_launch(void* const* d_in, const int* in_sizes, int n_in,
                              void* d_out, int out_size, void* d_ws, size_t ws_size,
                              hipStream_t stream) {
    const float* xa   = (const float*)d_in[0];
    const float* xb   = (const float*)d_in[1];
    const int* ei_ab  = (const int*)d_in[2];
    const int* ei_ba  = (const int*)d_in[3];
    const int* ei_aa  = (const int*)d_in[4];
    const float* Wk   = (const float*)d_in[5];
    const float* bk   = (const float*)d_in[6];
    const float* Wq   = (const float*)d_in[7];
    const float* bq   = (const float*)d_in[8];
    const float* Wv   = (const float*)d_in[9];
    const float* bv   = (const float*)d_in[10];
    const float* Wa   = (const float*)d_in[11];
    const float* ba   = (const float*)d_in[12];
    const float* skip = (const float*)d_in[13];
    const float* arel = (const float*)d_in[14];
    const float* mrel = (const float*)d_in[15];
    const float* prel = (const float*)d_in[16];

    const int NA = in_sizes[0] / F;
    const int NB = in_sizes[1] / F;
    const int Es[3] = {in_sizes[2] / 2, in_sizes[3] / 2, in_sizes[4] / 2};
    const int Nmax = NA > NB ? NA : NB;

    float* ws = (float*)d_ws;
    size_t o = 0;
    float* q0   = ws + o; o += (size_t)NA * F;
    float* q1   = ws + o; o += (size_t)NB * F;
    float* krel = ws + o; o += (size_t)Nmax * F;
    float* vrel = ws + o; o += (size_t)Nmax * F;
    float* agg0 = ws + o; o += (size_t)NA * F;
    float* agg1 = ws + o; o += (size_t)NB * F;
    float* x1a  = ws + o; o += (size_t)NA * F;
    float* x1b  = ws + o; o += (size_t)NB * F;
    float* bfk  = ws + o; o += 3 * 128;
    float* bfv  = ws + o; o += 3 * 128;
    // ints
    int* iws = (int*)(ws + o);
    size_t io = 0;
    int* cnt  = iws + io; io += Nmax;
    int* bsum = iws + io; io += 1024;
    int* csr_off[3]; int* csr_woff[3]; int* csr_src[3];
    for (int e = 0; e < 3; ++e) {
        csr_off[e]  = iws + io; io += Nmax + 1;
        csr_woff[e] = iws + io; io += Nmax;
        csr_src[e]  = iws + io; io += Es[e];
    }
    io = (io + 7) & ~(size_t)7;   // 32B align for bf16 weight slots
    short* sws = (short*)(iws + io);
    short* Wt4 = sws;                 // q0,q1,a0,a1
    short* Wtk = sws + (size_t)4 * 16384;
    short* Wtv = sws + (size_t)7 * 16384;

    float* outA = (float*)d_out;
    float* outB = (float*)d_out + (size_t)NA * F;

    const int* eis[3] = {ei_ab, ei_ba, ei_aa};
    const int Nds[3] = {NB, NA, NA};

    // ---- CSR once per edge type ----
    for (int e = 0; e < 3; ++e) {
        int Ee = Es[e], Nd = Nds[e];
        const int* dstp = eis[e] + Ee;
        int nb = cdiv(Nd, 256);
        hipMemsetAsync(cnt, 0, (size_t)Nd * sizeof(int), stream);
        hist_kernel<<<cdiv(Ee, 256), 256, 0, stream>>>(dstp, Ee, cnt);
        scan1<<<nb, 256, 0, stream>>>(cnt, Nd, csr_off[e], bsum);
        scan2<<<1, 1024, 0, stream>>>(bsum, nb, csr_off[e] + Nd);
        scan3<<<nb, 256, 0, stream>>>(csr_off[e], csr_woff[e], bsum, Nd);
        scatter_kernel<<<cdiv(Ee, 256), 256, 0, stream>>>(eis[e], dstp, Ee, csr_woff[e], csr_src[e]);
    }

    for (int l = 0; l < 2; ++l) {
        const float* x0 = l ? x1a : xa;
        const float* x1 = l ? x1b : xb;

        conv_wt4<<<cdiv(4 * 16384, 256), 256, 0, stream>>>(Wq, Wa, l, Wt4);
        build_fused_bf<<<cdiv(2 * 3 * 128 * 128 + 2 * 3 * 128, 256), 256, 0, stream>>>(
            Wk, bk, Wv, bv, arel, mrel, l, Wtk, Wtv, bfk, bfv);

        gemm_mfma<0><<<cdiv(NA, 64), 256, 0, stream>>>(x0, Wt4 + 0 * 16384,
            bq + (size_t)(l * 2 + 0) * F, nullptr, nullptr, q0, NA, 0);
        gemm_mfma<0><<<cdiv(NB, 64), 256, 0, stream>>>(x1, Wt4 + 1 * 16384,
            bq + (size_t)(l * 2 + 1) * F, nullptr, nullptr, q1, NB, 0);

        hipMemsetAsync(agg0, 0, (size_t)NA * F * sizeof(float), stream);
        hipMemsetAsync(agg1, 0, (size_t)NB * F * sizeof(float), stream);

        for (int e = 0; e < 3; ++e) {
            const float* xs = (e == 1) ? x1 : x0;
            int Ns = (e == 1) ? NB : NA;
            int Nd = Nds[e];
            const float* qd = (e == 0) ? q1 : q0;
            float* aggd = (e == 0) ? agg1 : agg0;

            gemm_mfma<0><<<cdiv(Ns, 64), 256, 0, stream>>>(xs, Wtk + (size_t)e * 16384,
                bfk + e * 128, nullptr, nullptr, krel, Ns, 0);
            gemm_mfma<0><<<cdiv(Ns, 64), 256, 0, stream>>>(xs, Wtv + (size_t)e * 16384,
                bfv + e * 128, nullptr, nullptr, vrel, Ns, 0);

            seg_attn<<<cdiv(Nd, 2), 256, 0, stream>>>(qd, krel, vrel,
                csr_off[e], csr_src[e], prel + (size_t)(l * 3 + e) * NH, aggd, Nd);
        }

        float* o0 = l ? outA : x1a;
        float* o1 = l ? outB : x1b;
        gemm_mfma<1><<<cdiv(NA, 64), 256, 0, stream>>>(agg0, Wt4 + 2 * 16384,
            ba + (size_t)(l * 2 + 0) * F, x0, skip + l * 2 + 0, o0, NA, l == 0 ? 1 : 0);
        gemm_mfma<1><<<cdiv(NB, 64), 256, 0, stream>>>(agg1, Wt4 + 3 * 16384,
            ba + (size_t)(l * 2 + 1) * F, x1, skip + l * 2 + 1, o1, NB, l == 0 ? 1 : 0);
    }
}

// Round 4
// 611.018 us; speedup vs baseline: 16.7168x; 1.5760x over previous
//
#include <hip/hip_runtime.h>
#include <hip/hip_bf16.h>
#include <math.h>

#define F 128
#define NH 8
#define HD 16

static inline int cdiv(int a, int b) { return (a + b - 1) / b; }

typedef __attribute__((ext_vector_type(8))) short bf16x8;
typedef __attribute__((ext_vector_type(4))) float f32x4;

__device__ __forceinline__ float geluf(float x) {
    return 0.5f * x * (1.f + erff(x * 0.70710678118654752440f));
}

__device__ __forceinline__ short f2bf(float f) {
    __hip_bfloat16 h = __float2bfloat16(f);
    return *reinterpret_cast<short*>(&h);
}

__device__ __forceinline__ float bf2f(short s) {
    return __uint_as_float(((unsigned int)(unsigned short)s) << 16);
}

// ---- weight prep: 10 slots of bf16 [n][k] + 10 f32 bias slots -------------
// slot: 0 q(t0) | 1 k-fused e0 | 2 v-fused e0 | 3 k-fused e2 | 4 v-fused e2
//       5 q(t1) | 6 k-fused e1 | 7 v-fused e1 | 8 a(t0) | 9 a(t1)
__device__ __forceinline__ void slot_info(int slot, int& kind, int& wsel, int& e, int& t) {
    switch (slot) {
        case 0: kind = 0; wsel = 0; t = 0; e = 0; break;
        case 1: kind = 1; wsel = 1; t = 0; e = 0; break;
        case 2: kind = 1; wsel = 2; t = 0; e = 0; break;
        case 3: kind = 1; wsel = 1; t = 0; e = 2; break;
        case 4: kind = 1; wsel = 2; t = 0; e = 2; break;
        case 5: kind = 0; wsel = 0; t = 1; e = 0; break;
        case 6: kind = 1; wsel = 1; t = 1; e = 1; break;
        case 7: kind = 1; wsel = 2; t = 1; e = 1; break;
        case 8: kind = 0; wsel = 3; t = 0; e = 0; break;
        default: kind = 0; wsel = 3; t = 1; e = 0; break;
    }
}

__global__ void prep_weights(const float* __restrict__ Wk, const float* __restrict__ bk,
                             const float* __restrict__ Wq, const float* __restrict__ bq,
                             const float* __restrict__ Wv, const float* __restrict__ bv,
                             const float* __restrict__ Wa, const float* __restrict__ ba,
                             const float* __restrict__ arel, const float* __restrict__ mrel,
                             int layer, short* __restrict__ Wslots, float* __restrict__ bslots) {
    const int WTOT = 10 * 16384;
    int idx = blockIdx.x * blockDim.x + threadIdx.x;
    if (idx < WTOT) {
        int slot = idx >> 14, rem = idx & 16383;
        int n = rem >> 7, k = rem & 127;
        int kind, wsel, e, t;
        slot_info(slot, kind, wsel, e, t);
        float out;
        if (kind == 0) {
            const float* Wb = (wsel == 0 ? Wq : Wa) + (size_t)(layer * 2 + t) * 16384;
            out = Wb[k * 128 + n];
        } else {
            int h = n >> 4, j = n & 15;
            const float* Wb = (wsel == 1 ? Wk : Wv) + (size_t)(layer * 2 + t) * 16384;
            const float* R = (wsel == 1 ? arel : mrel) + (size_t)((layer * 3 + e) * NH + h) * 256;
            float s = 0.f;
            #pragma unroll
            for (int d = 0; d < HD; ++d) s += Wb[k * 128 + h * 16 + d] * R[d * 16 + j];
            out = s;
        }
        Wslots[(size_t)slot * 16384 + n * 128 + k] = f2bf(out);
    } else {
        int r = idx - WTOT;
        if (r < 10 * 128) {
            int slot = r >> 7, n = r & 127;
            int kind, wsel, e, t;
            slot_info(slot, kind, wsel, e, t);
            float out;
            if (kind == 0) {
                const float* bb = (wsel == 0 ? bq : ba) + (size_t)(layer * 2 + t) * 128;
                out = bb[n];
            } else {
                int h = n >> 4, j = n & 15;
                const float* bb = (wsel == 1 ? bk : bv) + (size_t)(layer * 2 + t) * 128;
                const float* R = (wsel == 1 ? arel : mrel) + (size_t)((layer * 3 + e) * NH + h) * 256;
                float s = 0.f;
                #pragma unroll
                for (int d = 0; d < HD; ++d) s += bb[h * 16 + d] * R[d * 16 + j];
                out = s;
            }
            bslots[slot * 128 + n] = out;
        }
    }
}

// ---- batched MFMA GEMM over shared A: y-slot picks W/bias/output ----------
// C_y[N,128](bf16) = A[N,128](f32) @ W_y + bias_y
__global__ __launch_bounds__(256) void gemm_qkv(
    const float* __restrict__ A, const short* __restrict__ Wts,
    const float* __restrict__ biases, short* __restrict__ Cs, int N) {
    __shared__ short Ws[128 * 136];
    __shared__ short As[64 * 136];
    const int tid = threadIdx.x;
    const int row0 = blockIdx.x * 64;
    const short* Wt = Wts + (size_t)blockIdx.y * 16384;
    const float* bias = biases + (size_t)blockIdx.y * 128;
    short* C = Cs + (size_t)blockIdx.y * (size_t)N * F;

    #pragma unroll
    for (int it = 0; it < 8; ++it) {
        int chunk = tid + it * 256;
        int r = chunk >> 4, c8 = (chunk & 15) * 8;
        *(int4*)&Ws[r * 136 + c8] = *(const int4*)&Wt[r * 128 + c8];
    }
    #pragma unroll
    for (int it = 0; it < 4; ++it) {
        int chunk = tid + it * 256;
        int r = chunk >> 4, c8 = (chunk & 15) * 8;
        int gr = row0 + r;
        bf16x8 s = {};
        if (gr < N) {
            float4 v0 = *(const float4*)&A[(size_t)gr * F + c8];
            float4 v1 = *(const float4*)&A[(size_t)gr * F + c8 + 4];
            s[0] = f2bf(v0.x); s[1] = f2bf(v0.y); s[2] = f2bf(v0.z); s[3] = f2bf(v0.w);
            s[4] = f2bf(v1.x); s[5] = f2bf(v1.y); s[6] = f2bf(v1.z); s[7] = f2bf(v1.w);
        }
        *(bf16x8*)&As[r * 136 + c8] = s;
    }
    __syncthreads();

    const int wave = tid >> 6;
    const int lane = tid & 63;
    const int m16 = lane & 15;
    const int kg = lane >> 4;
    const int arow = wave * 16 + m16;

    f32x4 acc[8] = {};
    #pragma unroll
    for (int k0 = 0; k0 < 128; k0 += 32) {
        bf16x8 a = *(const bf16x8*)&As[arow * 136 + k0 + kg * 8];
        #pragma unroll
        for (int nt = 0; nt < 8; ++nt) {
            bf16x8 b = *(const bf16x8*)&Ws[(nt * 16 + m16) * 136 + k0 + kg * 8];
            acc[nt] = __builtin_amdgcn_mfma_f32_16x16x32_bf16(a, b, acc[nt], 0, 0, 0);
        }
    }

    #pragma unroll
    for (int nt = 0; nt < 8; ++nt) {
        int n = nt * 16 + m16;
        float bl = bias[n];
        #pragma unroll
        for (int r = 0; r < 4; ++r) {
            int gr = row0 + wave * 16 + kg * 4 + r;
            if (gr >= N) continue;
            C[(size_t)gr * F + n] = f2bf(acc[nt][r] + bl);
        }
    }
}

// ---- out-projection: C[N,128](f32) = gelu(Agg bf16) @ W + bias, skip-gate --
__global__ __launch_bounds__(256) void gemm_out(
    const short* __restrict__ A, const short* __restrict__ Wt,
    const float* __restrict__ bias, const float* __restrict__ xres,
    const float* __restrict__ skipp, float* __restrict__ C, int N, int do_relu) {
    __shared__ short Ws[128 * 136];
    __shared__ short As[64 * 136];
    const int tid = threadIdx.x;
    const int row0 = blockIdx.x * 64;

    #pragma unroll
    for (int it = 0; it < 8; ++it) {
        int chunk = tid + it * 256;
        int r = chunk >> 4, c8 = (chunk & 15) * 8;
        *(int4*)&Ws[r * 136 + c8] = *(const int4*)&Wt[r * 128 + c8];
    }
    #pragma unroll
    for (int it = 0; it < 4; ++it) {
        int chunk = tid + it * 256;
        int r = chunk >> 4, c8 = (chunk & 15) * 8;
        int gr = row0 + r;
        bf16x8 s = {};
        if (gr < N) {
            s = *(const bf16x8*)&A[(size_t)gr * F + c8];
            #pragma unroll
            for (int u = 0; u < 8; ++u) s[u] = f2bf(geluf(bf2f(s[u])));
        }
        *(bf16x8*)&As[r * 136 + c8] = s;
    }
    __syncthreads();

    const int wave = tid >> 6;
    const int lane = tid & 63;
    const int m16 = lane & 15;
    const int kg = lane >> 4;
    const int arow = wave * 16 + m16;

    f32x4 acc[8] = {};
    #pragma unroll
    for (int k0 = 0; k0 < 128; k0 += 32) {
        bf16x8 a = *(const bf16x8*)&As[arow * 136 + k0 + kg * 8];
        #pragma unroll
        for (int nt = 0; nt < 8; ++nt) {
            bf16x8 b = *(const bf16x8*)&Ws[(nt * 16 + m16) * 136 + k0 + kg * 8];
            acc[nt] = __builtin_amdgcn_mfma_f32_16x16x32_bf16(a, b, acc[nt], 0, 0, 0);
        }
    }

    float sg = 1.f / (1.f + expf(-skipp[0]));
    #pragma unroll
    for (int nt = 0; nt < 8; ++nt) {
        int n = nt * 16 + m16;
        float bl = bias[n];
        #pragma unroll
        for (int r = 0; r < 4; ++r) {
            int gr = row0 + wave * 16 + kg * 4 + r;
            if (gr >= N) continue;
            float v = acc[nt][r] + bl;
            float xr = xres[(size_t)gr * F + n];
            v = sg * v + (1.f - sg) * xr;
            if (do_relu) v = fmaxf(v, 0.f);
            C[(size_t)gr * F + n] = v;
        }
    }
}

// ---------------- CSR build --------------------------------------------------

__global__ void hist_kernel(const int* __restrict__ dst, int E, int* __restrict__ cnt) {
    int i = blockIdx.x * blockDim.x + threadIdx.x;
    if (i < E) atomicAdd(&cnt[dst[i]], 1);
}

__global__ void scan1(const int* __restrict__ cnt, int n, int* __restrict__ off,
                      int* __restrict__ bsum) {
    __shared__ int lds[256];
    int tid = threadIdx.x, i = blockIdx.x * 256 + tid;
    int v = (i < n) ? cnt[i] : 0;
    lds[tid] = v;
    __syncthreads();
    #pragma unroll
    for (int s = 1; s < 256; s <<= 1) {
        int t = (tid >= s) ? lds[tid - s] : 0;
        __syncthreads();
        lds[tid] += t;
        __syncthreads();
    }
    if (i < n) off[i] = lds[tid] - v;
    if (tid == 255) bsum[blockIdx.x] = lds[255];
}

__global__ __launch_bounds__(1024) void scan2(int* __restrict__ bsum, int nb,
                                              int* __restrict__ off_n) {
    __shared__ int lds[1024];
    int tid = threadIdx.x;
    int v = (tid < nb) ? bsum[tid] : 0;
    lds[tid] = v;
    __syncthreads();
    #pragma unroll
    for (int s = 1; s < 1024; s <<= 1) {
        int t = (tid >= s) ? lds[tid - s] : 0;
        __syncthreads();
        lds[tid] += t;
        __syncthreads();
    }
    if (tid < nb) bsum[tid] = lds[tid] - v;
    if (tid == 1023) *off_n = lds[1023];
}

__global__ void scan3(int* __restrict__ off, int* __restrict__ woff,
                      const int* __restrict__ bsum, int n) {
    int i = blockIdx.x * 256 + threadIdx.x;
    if (i < n) {
        int v = off[i] + bsum[blockIdx.x];
        off[i] = v;
        woff[i] = v;
    }
}

__global__ void scatter_kernel(const int* __restrict__ src, const int* __restrict__ dst,
                               int E, int* __restrict__ woff, int* __restrict__ csr_src) {
    int i = blockIdx.x * blockDim.x + threadIdx.x;
    if (i < E) {
        int p = atomicAdd(&woff[dst[i]], 1);
        csr_src[p] = src[i];
    }
}

// ---- fused segment attention, bf16, wave-per-dst, NSET edge groups ---------
template <int NSET>
__global__ __launch_bounds__(256) void seg_attn_bf(
    const short* __restrict__ q,
    const short* __restrict__ k1, const short* __restrict__ v1,
    const int* __restrict__ off1, const int* __restrict__ src1,
    const short* __restrict__ k2, const short* __restrict__ v2,
    const int* __restrict__ off2, const int* __restrict__ src2,
    const float* __restrict__ prel1, const float* __restrict__ prel2,
    short* __restrict__ agg, int Nd) {
    int dst = blockIdx.x * 4 + (threadIdx.x >> 6);
    if (dst >= Nd) return;
    int l = threadIdx.x & 63;
    int h = l >> 3;                      // 8 lanes per head, 2 dims per lane
    unsigned int qu = ((const unsigned int*)(q + (size_t)dst * F))[l];
    float qlo = __uint_as_float(qu << 16);
    float qhi = __uint_as_float(qu & 0xffff0000u);
    float rlo = 0.f, rhi = 0.f;
    #pragma unroll
    for (int s = 0; s < NSET; ++s) {
        const short* kk = s ? k2 : k1;
        const short* vv = s ? v2 : v1;
        const int* off = s ? off2 : off1;
        const int* srcp = s ? src2 : src1;
        float pr = (s ? prel2[h] : prel1[h]) * 0.25f;
        int e0 = off[dst], e1 = off[dst + 1];
        float m = -INFINITY, den = 0.f, alo = 0.f, ahi = 0.f;
        for (int j = e0; j < e1; ++j) {
            int sj = __builtin_amdgcn_readfirstlane(srcp[j]);
            unsigned int ku = ((const unsigned int*)(kk + (size_t)sj * F))[l];
            unsigned int vu = ((const unsigned int*)(vv + (size_t)sj * F))[l];
            float p = __uint_as_float(ku << 16) * qlo + __uint_as_float(ku & 0xffff0000u) * qhi;
            p += __shfl_xor(p, 4, 8);
            p += __shfl_xor(p, 2, 8);
            p += __shfl_xor(p, 1, 8);
            float alpha = p * pr;
            float nm = fmaxf(m, alpha);
            float corr = __expf(m - nm);
            float ex = __expf(alpha - nm);
            den = den * corr + ex;
            alo = alo * corr + ex * __uint_as_float(vu << 16);
            ahi = ahi * corr + ex * __uint_as_float(vu & 0xffff0000u);
            m = nm;
        }
        float inv = 1.f / (den + 1e-16f);
        rlo += alo * inv;
        rhi += ahi * inv;
    }
    unsigned int plo = (unsigned int)(unsigned short)f2bf(rlo);
    unsigned int phi = (unsigned int)(unsigned short)f2bf(rhi);
    ((unsigned int*)(agg + (size_t)dst * F))[l] = plo | (phi << 16);
}

extern "C" void kernel_launch(void* const* d_in, const int* in_sizes, int n_in,
                              void* d_out, int out_size, void* d_ws, size_t ws_size,
                              hipStream_t stream) {
    const float* xa   = (const float*)d_in[0];
    const float* xb   = (const float*)d_in[1];
    const int* ei_ab  = (const int*)d_in[2];
    const int* ei_ba  = (const int*)d_in[3];
    const int* ei_aa  = (const int*)d_in[4];
    const float* Wk   = (const float*)d_in[5];
    const float* bk   = (const float*)d_in[6];
    const float* Wq   = (const float*)d_in[7];
    const float* bq   = (const float*)d_in[8];
    const float* Wv   = (const float*)d_in[9];
    const float* bv   = (const float*)d_in[10];
    const float* Wa   = (const float*)d_in[11];
    const float* ba   = (const float*)d_in[12];
    const float* skip = (const float*)d_in[13];
    const float* arel = (const float*)d_in[14];
    const float* mrel = (const float*)d_in[15];
    const float* prel = (const float*)d_in[16];

    const int NA = in_sizes[0] / F;
    const int NB = in_sizes[1] / F;
    const int Es[3] = {in_sizes[2] / 2, in_sizes[3] / 2, in_sizes[4] / 2};
    const int Nmax = NA > NB ? NA : NB;

    float* ws = (float*)d_ws;
    size_t o = 0;
    float* x1a   = ws + o; o += (size_t)NA * F;
    float* x1b   = ws + o; o += (size_t)NB * F;
    float* bslots= ws + o; o += 10 * 128;
    // ints
    int* iws = (int*)(ws + o);
    size_t io = 0;
    int* cnt  = iws + io; io += Nmax;
    int* bsum = iws + io; io += 1024;
    int* csr_off[3]; int* csr_woff[3]; int* csr_src[3];
    for (int e = 0; e < 3; ++e) {
        csr_off[e]  = iws + io; io += Nmax + 1;
        csr_woff[e] = iws + io; io += Nmax;
        csr_src[e]  = iws + io; io += Es[e];
    }
    io = (io + 7) & ~(size_t)7;
    // shorts (bf16)
    short* sws = (short*)(iws + io);
    size_t so = 0;
    short* bufA  = sws + so; so += (size_t)5 * NA * F;   // q0,k0,v0,k2,v2
    short* bufB  = sws + so; so += (size_t)3 * NB * F;   // q1,k1,v1
    short* aggA  = sws + so; so += (size_t)NA * F;
    short* aggB  = sws + so; so += (size_t)NB * F;
    short* Wslots= sws + so; so += (size_t)10 * 16384;

    float* outA = (float*)d_out;
    float* outB = (float*)d_out + (size_t)NA * F;

    const int* eis[3] = {ei_ab, ei_ba, ei_aa};
    const int Nds[3] = {NB, NA, NA};

    // ---- CSR once per edge type ----
    for (int e = 0; e < 3; ++e) {
        int Ee = Es[e], Nd = Nds[e];
        const int* dstp = eis[e] + Ee;
        int nb = cdiv(Nd, 256);
        hipMemsetAsync(cnt, 0, (size_t)Nd * sizeof(int), stream);
        hist_kernel<<<cdiv(Ee, 256), 256, 0, stream>>>(dstp, Ee, cnt);
        scan1<<<nb, 256, 0, stream>>>(cnt, Nd, csr_off[e], bsum);
        scan2<<<1, 1024, 0, stream>>>(bsum, nb, csr_off[e] + Nd);
        scan3<<<nb, 256, 0, stream>>>(csr_off[e], csr_woff[e], bsum, Nd);
        scatter_kernel<<<cdiv(Ee, 256), 256, 0, stream>>>(eis[e], dstp, Ee, csr_woff[e], csr_src[e]);
    }

    for (int l = 0; l < 2; ++l) {
        const float* x0 = l ? x1a : xa;
        const float* x1 = l ? x1b : xb;

        prep_weights<<<cdiv(10 * 16384 + 10 * 128, 256), 256, 0, stream>>>(
            Wk, bk, Wq, bq, Wv, bv, Wa, ba, arel, mrel, l, Wslots, bslots);

        // x0-group: q0,k0,v0,k2,v2 ; x1-group: q1,k1,v1
        {
            dim3 g0(cdiv(NA, 64), 5);
            gemm_qkv<<<g0, 256, 0, stream>>>(x0, Wslots, bslots, bufA, NA);
            dim3 g1(cdiv(NB, 64), 3);
            gemm_qkv<<<g1, 256, 0, stream>>>(x1, Wslots + (size_t)5 * 16384,
                                             bslots + 5 * 128, bufB, NB);
        }

        const short* q0 = bufA;
        const short* k0 = bufA + (size_t)1 * NA * F;
        const short* v0 = bufA + (size_t)2 * NA * F;
        const short* k2 = bufA + (size_t)3 * NA * F;
        const short* v2 = bufA + (size_t)4 * NA * F;
        const short* q1 = bufB;
        const short* k1 = bufB + (size_t)1 * NB * F;
        const short* v1 = bufB + (size_t)2 * NB * F;

        // dst type b: e0 only
        seg_attn_bf<1><<<cdiv(NB, 4), 256, 0, stream>>>(
            q1, k0, v0, csr_off[0], csr_src[0],
            nullptr, nullptr, nullptr, nullptr,
            prel + (size_t)(l * 3 + 0) * NH, nullptr, aggB, NB);
        // dst type a: e1 + e2
        seg_attn_bf<2><<<cdiv(NA, 4), 256, 0, stream>>>(
            q0, k1, v1, csr_off[1], csr_src[1],
            k2, v2, csr_off[2], csr_src[2],
            prel + (size_t)(l * 3 + 1) * NH, prel + (size_t)(l * 3 + 2) * NH, aggA, NA);

        float* o0 = l ? outA : x1a;
        float* o1 = l ? outB : x1b;
        gemm_out<<<cdiv(NA, 64), 256, 0, stream>>>(aggA, Wslots + (size_t)8 * 16384,
            bslots + 8 * 128, x0, skip + l * 2 + 0, o0, NA, l == 0 ? 1 : 0);
        gemm_out<<<cdiv(NB, 64), 256, 0, stream>>>(aggB, Wslots + (size_t)9 * 16384,
            bslots + 9 * 128, x1, skip + l * 2 + 1, o1, NB, l == 0 ? 1 : 0);
    }
}

// Round 5
// 551.785 us; speedup vs baseline: 18.5113x; 1.1073x over previous
//
#include <hip/hip_runtime.h>
#include <hip/hip_bf16.h>
#include <math.h>

#define F 128
#define NH 8
#define HD 16

static inline int cdiv(int a, int b) { return (a + b - 1) / b; }

typedef __attribute__((ext_vector_type(8))) short bf16x8;
typedef __attribute__((ext_vector_type(4))) float f32x4;

__device__ __forceinline__ float geluf(float x) {
    return 0.5f * x * (1.f + erff(x * 0.70710678118654752440f));
}

__device__ __forceinline__ short f2bf(float f) {
    __hip_bfloat16 h = __float2bfloat16(f);
    return *reinterpret_cast<short*>(&h);
}

__device__ __forceinline__ float bflo(unsigned int u) { return __uint_as_float(u << 16); }
__device__ __forceinline__ float bfhi(unsigned int u) { return __uint_as_float(u & 0xffff0000u); }

// ---- weight prep: per layer 10 slots of bf16 [n][k] + 10 f32 bias slots ----
// slot: 0 q(t0) | 1 k-fused e0 | 2 v-fused e0 | 3 k-fused e2 | 4 v-fused e2
//       5 q(t1) | 6 k-fused e1 | 7 v-fused e1 | 8 a(t0) | 9 a(t1)
__device__ __forceinline__ void slot_info(int slot, int& kind, int& wsel, int& e, int& t) {
    switch (slot) {
        case 0: kind = 0; wsel = 0; t = 0; e = 0; break;
        case 1: kind = 1; wsel = 1; t = 0; e = 0; break;
        case 2: kind = 1; wsel = 2; t = 0; e = 0; break;
        case 3: kind = 1; wsel = 1; t = 0; e = 2; break;
        case 4: kind = 1; wsel = 2; t = 0; e = 2; break;
        case 5: kind = 0; wsel = 0; t = 1; e = 0; break;
        case 6: kind = 1; wsel = 1; t = 1; e = 1; break;
        case 7: kind = 1; wsel = 2; t = 1; e = 1; break;
        case 8: kind = 0; wsel = 3; t = 0; e = 0; break;
        default: kind = 0; wsel = 3; t = 1; e = 0; break;
    }
}

__global__ void prep_weights(const float* __restrict__ Wk, const float* __restrict__ bk,
                             const float* __restrict__ Wq, const float* __restrict__ bq,
                             const float* __restrict__ Wv, const float* __restrict__ bv,
                             const float* __restrict__ Wa, const float* __restrict__ ba,
                             const float* __restrict__ arel, const float* __restrict__ mrel,
                             short* __restrict__ Wslots, float* __restrict__ bslots) {
    const int WTOT = 10 * 16384;
    const int layer = blockIdx.y;
    short* Wl = Wslots + (size_t)layer * WTOT;
    float* bl = bslots + (size_t)layer * 10 * 128;
    int idx = blockIdx.x * blockDim.x + threadIdx.x;
    if (idx < WTOT) {
        int slot = idx >> 14, rem = idx & 16383;
        int n = rem >> 7, k = rem & 127;
        int kind, wsel, e, t;
        slot_info(slot, kind, wsel, e, t);
        float out;
        if (kind == 0) {
            const float* Wb = (wsel == 0 ? Wq : Wa) + (size_t)(layer * 2 + t) * 16384;
            out = Wb[k * 128 + n];
        } else {
            int h = n >> 4, j = n & 15;
            const float* Wb = (wsel == 1 ? Wk : Wv) + (size_t)(layer * 2 + t) * 16384;
            const float* R = (wsel == 1 ? arel : mrel) + (size_t)((layer * 3 + e) * NH + h) * 256;
            float s = 0.f;
            #pragma unroll
            for (int d = 0; d < HD; ++d) s += Wb[k * 128 + h * 16 + d] * R[d * 16 + j];
            out = s;
        }
        Wl[(size_t)slot * 16384 + n * 128 + k] = f2bf(out);
    } else {
        int r = idx - WTOT;
        if (r < 10 * 128) {
            int slot = r >> 7, n = r & 127;
            int kind, wsel, e, t;
            slot_info(slot, kind, wsel, e, t);
            float out;
            if (kind == 0) {
                const float* bb = (wsel == 0 ? bq : ba) + (size_t)(layer * 2 + t) * 128;
                out = bb[n];
            } else {
                int h = n >> 4, j = n & 15;
                const float* bb = (wsel == 1 ? bk : bv) + (size_t)(layer * 2 + t) * 128;
                const float* R = (wsel == 1 ? arel : mrel) + (size_t)((layer * 3 + e) * NH + h) * 256;
                float s = 0.f;
                #pragma unroll
                for (int d = 0; d < HD; ++d) s += bb[h * 16 + d] * R[d * 16 + j];
                out = s;
            }
            bl[slot * 128 + n] = out;
        }
    }
}

// ---- batched MFMA GEMM over shared A (f32 or bf16): y-slot picks W/bias/out
template <typename AT>
__global__ __launch_bounds__(256) void gemm_qkv(
    const AT* __restrict__ A, const short* __restrict__ Wts,
    const float* __restrict__ biases, short* __restrict__ Cs, int N) {
    __shared__ short Ws[128 * 136];
    __shared__ short As[64 * 136];
    const int tid = threadIdx.x;
    const int row0 = blockIdx.x * 64;
    const short* Wt = Wts + (size_t)blockIdx.y * 16384;
    const float* bias = biases + (size_t)blockIdx.y * 128;
    short* C = Cs + (size_t)blockIdx.y * (size_t)N * F;

    #pragma unroll
    for (int it = 0; it < 8; ++it) {
        int chunk = tid + it * 256;
        int r = chunk >> 4, c8 = (chunk & 15) * 8;
        *(int4*)&Ws[r * 136 + c8] = *(const int4*)&Wt[r * 128 + c8];
    }
    #pragma unroll
    for (int it = 0; it < 4; ++it) {
        int chunk = tid + it * 256;
        int r = chunk >> 4, c8 = (chunk & 15) * 8;
        int gr = row0 + r;
        bf16x8 s = {};
        if (gr < N) {
            if constexpr (sizeof(AT) == 4) {
                float4 v0 = *(const float4*)&A[(size_t)gr * F + c8];
                float4 v1 = *(const float4*)&A[(size_t)gr * F + c8 + 4];
                s[0] = f2bf(v0.x); s[1] = f2bf(v0.y); s[2] = f2bf(v0.z); s[3] = f2bf(v0.w);
                s[4] = f2bf(v1.x); s[5] = f2bf(v1.y); s[6] = f2bf(v1.z); s[7] = f2bf(v1.w);
            } else {
                s = *(const bf16x8*)&A[(size_t)gr * F + c8];
            }
        }
        *(bf16x8*)&As[r * 136 + c8] = s;
    }
    __syncthreads();

    const int wave = tid >> 6;
    const int lane = tid & 63;
    const int m16 = lane & 15;
    const int kg = lane >> 4;
    const int arow = wave * 16 + m16;

    f32x4 acc[8] = {};
    #pragma unroll
    for (int k0 = 0; k0 < 128; k0 += 32) {
        bf16x8 a = *(const bf16x8*)&As[arow * 136 + k0 + kg * 8];
        #pragma unroll
        for (int nt = 0; nt < 8; ++nt) {
            bf16x8 b = *(const bf16x8*)&Ws[(nt * 16 + m16) * 136 + k0 + kg * 8];
            acc[nt] = __builtin_amdgcn_mfma_f32_16x16x32_bf16(a, b, acc[nt], 0, 0, 0);
        }
    }

    #pragma unroll
    for (int nt = 0; nt < 8; ++nt) {
        int n = nt * 16 + m16;
        float bl = bias[n];
        #pragma unroll
        for (int r = 0; r < 4; ++r) {
            int gr = row0 + wave * 16 + kg * 4 + r;
            if (gr >= N) continue;
            C[(size_t)gr * F + n] = f2bf(acc[nt][r] + bl);
        }
    }
}

// ---- out-projection: o = gelu(Agg bf16) @ W + bias; out = sg*o+(1-sg)*xres
// OMODE 0: store f32 only (final). OMODE 1: store bf16 + f32, with relu.
template <int OMODE>
__global__ __launch_bounds__(256) void gemm_out(
    const short* __restrict__ A, const short* __restrict__ Wt,
    const float* __restrict__ bias, const float* __restrict__ xres,
    const float* __restrict__ skipp, float* __restrict__ Cf,
    short* __restrict__ Cb, int N) {
    __shared__ short Ws[128 * 136];
    __shared__ short As[64 * 136];
    const int tid = threadIdx.x;
    const int row0 = blockIdx.x * 64;

    #pragma unroll
    for (int it = 0; it < 8; ++it) {
        int chunk = tid + it * 256;
        int r = chunk >> 4, c8 = (chunk & 15) * 8;
        *(int4*)&Ws[r * 136 + c8] = *(const int4*)&Wt[r * 128 + c8];
    }
    #pragma unroll
    for (int it = 0; it < 4; ++it) {
        int chunk = tid + it * 256;
        int r = chunk >> 4, c8 = (chunk & 15) * 8;
        int gr = row0 + r;
        bf16x8 s = {};
        if (gr < N) {
            s = *(const bf16x8*)&A[(size_t)gr * F + c8];
            #pragma unroll
            for (int u = 0; u < 8; ++u)
                s[u] = f2bf(geluf(bflo(((unsigned int)(unsigned short)s[u]))));
        }
        *(bf16x8*)&As[r * 136 + c8] = s;
    }
    __syncthreads();

    const int wave = tid >> 6;
    const int lane = tid & 63;
    const int m16 = lane & 15;
    const int kg = lane >> 4;
    const int arow = wave * 16 + m16;

    f32x4 acc[8] = {};
    #pragma unroll
    for (int k0 = 0; k0 < 128; k0 += 32) {
        bf16x8 a = *(const bf16x8*)&As[arow * 136 + k0 + kg * 8];
        #pragma unroll
        for (int nt = 0; nt < 8; ++nt) {
            bf16x8 b = *(const bf16x8*)&Ws[(nt * 16 + m16) * 136 + k0 + kg * 8];
            acc[nt] = __builtin_amdgcn_mfma_f32_16x16x32_bf16(a, b, acc[nt], 0, 0, 0);
        }
    }

    float sg = 1.f / (1.f + expf(-skipp[0]));
    #pragma unroll
    for (int nt = 0; nt < 8; ++nt) {
        int n = nt * 16 + m16;
        float bl = bias[n];
        #pragma unroll
        for (int r = 0; r < 4; ++r) {
            int gr = row0 + wave * 16 + kg * 4 + r;
            if (gr >= N) continue;
            float v = acc[nt][r] + bl;
            float xr = xres[(size_t)gr * F + n];
            v = sg * v + (1.f - sg) * xr;
            if (OMODE == 1) {
                v = fmaxf(v, 0.f);
                Cb[(size_t)gr * F + n] = f2bf(v);
            }
            Cf[(size_t)gr * F + n] = v;
        }
    }
}

// ---------------- combined CSR build (all 3 edge types in one pass) ---------

__global__ void hist_all(const int* __restrict__ ei0, const int* __restrict__ ei1,
                         const int* __restrict__ ei2, int E0, int E1, int E2,
                         int NB_, int NA_, int* __restrict__ cnt) {
    int i = blockIdx.x * 256 + threadIdx.x;
    if (i >= E0 + E1 + E2) return;
    const int* ei; int li, Ee, base;
    if (i < E0)           { li = i;           ei = ei0; Ee = E0; base = 0; }
    else if (i < E0 + E1) { li = i - E0;      ei = ei1; Ee = E1; base = NB_; }
    else                  { li = i - E0 - E1; ei = ei2; Ee = E2; base = NB_ + NA_; }
    atomicAdd(&cnt[base + ei[Ee + li]], 1);
}

__global__ void scan1(const int* __restrict__ cnt, int n, int* __restrict__ off,
                      int* __restrict__ bsum) {
    __shared__ int lds[256];
    int tid = threadIdx.x, i = blockIdx.x * 256 + tid;
    int v = (i < n) ? cnt[i] : 0;
    lds[tid] = v;
    __syncthreads();
    #pragma unroll
    for (int s = 1; s < 256; s <<= 1) {
        int t = (tid >= s) ? lds[tid - s] : 0;
        __syncthreads();
        lds[tid] += t;
        __syncthreads();
    }
    if (i < n) off[i] = lds[tid] - v;
    if (tid == 255) bsum[blockIdx.x] = lds[255];
}

__global__ __launch_bounds__(1024) void scan2(int* __restrict__ bsum, int nb,
                                              int* __restrict__ off_n) {
    __shared__ int lds[1024];
    int tid = threadIdx.x;
    int v = (tid < nb) ? bsum[tid] : 0;
    lds[tid] = v;
    __syncthreads();
    #pragma unroll
    for (int s = 1; s < 1024; s <<= 1) {
        int t = (tid >= s) ? lds[tid - s] : 0;
        __syncthreads();
        lds[tid] += t;
        __syncthreads();
    }
    if (tid < nb) bsum[tid] = lds[tid] - v;
    if (tid == 1023) *off_n = lds[1023];
}

__global__ void scan3(int* __restrict__ off, int* __restrict__ woff,
                      const int* __restrict__ bsum, int n) {
    int i = blockIdx.x * 256 + threadIdx.x;
    if (i < n) {
        int v = off[i] + bsum[blockIdx.x];
        off[i] = v;
        woff[i] = v;
    }
}

__global__ void scatter_all(const int* __restrict__ ei0, const int* __restrict__ ei1,
                            const int* __restrict__ ei2, int E0, int E1, int E2,
                            int NB_, int NA_, int* __restrict__ woff,
                            int* __restrict__ csr_src) {
    int i = blockIdx.x * 256 + threadIdx.x;
    if (i >= E0 + E1 + E2) return;
    const int* ei; int li, Ee, base;
    if (i < E0)           { li = i;           ei = ei0; Ee = E0; base = 0; }
    else if (i < E0 + E1) { li = i - E0;      ei = ei1; Ee = E1; base = NB_; }
    else                  { li = i - E0 - E1; ei = ei2; Ee = E2; base = NB_ + NA_; }
    int p = atomicAdd(&woff[base + ei[Ee + li]], 1);
    csr_src[p] = ei[li];
}

// ---- fused segment attention, bf16, wave-per-dst, chunked-pipelined --------
// Chunk of 8 edges: batch all loads (8 src + 8 k-rows + 8 v-rows in flight),
// compute 8 alphas, single rescale per chunk (online softmax across chunks).
#define CH 8
template <int NSET>
__global__ __launch_bounds__(256) void seg_attn2(
    const short* __restrict__ q,
    const short* __restrict__ k1, const short* __restrict__ v1,
    const int* __restrict__ off1,
    const short* __restrict__ k2, const short* __restrict__ v2,
    const int* __restrict__ off2,
    const int* __restrict__ csr_src,
    const float* __restrict__ prel1, const float* __restrict__ prel2,
    short* __restrict__ agg, int Nd) {
    int dst = blockIdx.x * 4 + (threadIdx.x >> 6);
    if (dst >= Nd) return;
    int l = threadIdx.x & 63;
    int h = l >> 3;                      // 8 lanes per head, 2 dims per lane
    unsigned int qu = ((const unsigned int*)(q + (size_t)dst * F))[l];
    float qlo = bflo(qu), qhi = bfhi(qu);
    float rlo = 0.f, rhi = 0.f;
    #pragma unroll
    for (int s = 0; s < NSET; ++s) {
        const short* kk = s ? k2 : k1;
        const short* vv = s ? v2 : v1;
        const int* off = s ? off2 : off1;
        float pr = (s ? prel2[h] : prel1[h]) * 0.25f;
        int e0 = off[dst], e1 = off[dst + 1];
        float m = -INFINITY, den = 0.f, alo = 0.f, ahi = 0.f;
        for (int base = e0; base < e1; base += CH) {
            int n = e1 - base; if (n > CH) n = CH;
            int sj[CH];
            unsigned int ku[CH], vu[CH];
            #pragma unroll
            for (int c = 0; c < CH; ++c) if (c < n) sj[c] = csr_src[base + c];
            #pragma unroll
            for (int c = 0; c < CH; ++c) if (c < n) {
                ku[c] = ((const unsigned int*)(kk + (size_t)sj[c] * F))[l];
                vu[c] = ((const unsigned int*)(vv + (size_t)sj[c] * F))[l];
            }
            float al[CH];
            float cmax = -INFINITY;
            #pragma unroll
            for (int c = 0; c < CH; ++c) if (c < n) {
                float p = bflo(ku[c]) * qlo + bfhi(ku[c]) * qhi;
                p += __shfl_xor(p, 4, 8);
                p += __shfl_xor(p, 2, 8);
                p += __shfl_xor(p, 1, 8);
                al[c] = p * pr;
                cmax = fmaxf(cmax, al[c]);
            }
            float nm = fmaxf(m, cmax);
            float corr = __expf(m - nm);   // first chunk: exp(-inf)=0
            den *= corr; alo *= corr; ahi *= corr;
            #pragma unroll
            for (int c = 0; c < CH; ++c) if (c < n) {
                float ex = __expf(al[c] - nm);
                den += ex;
                alo = fmaf(ex, bflo(vu[c]), alo);
                ahi = fmaf(ex, bfhi(vu[c]), ahi);
            }
            m = nm;
        }
        float inv = 1.f / (den + 1e-16f);
        rlo = fmaf(alo, inv, rlo);
        rhi = fmaf(ahi, inv, rhi);
    }
    unsigned int plo = (unsigned int)(unsigned short)f2bf(rlo);
    unsigned int phi = (unsigned int)(unsigned short)f2bf(rhi);
    ((unsigned int*)(agg + (size_t)dst * F))[l] = plo | (phi << 16);
}

extern "C" void kernel_launch(void* const* d_in, const int* in_sizes, int n_in,
                              void* d_out, int out_size, void* d_ws, size_t ws_size,
                              hipStream_t stream) {
    const float* xa   = (const float*)d_in[0];
    const float* xb   = (const float*)d_in[1];
    const int* ei_ab  = (const int*)d_in[2];
    const int* ei_ba  = (const int*)d_in[3];
    const int* ei_aa  = (const int*)d_in[4];
    const float* Wk   = (const float*)d_in[5];
    const float* bk   = (const float*)d_in[6];
    const float* Wq   = (const float*)d_in[7];
    const float* bq   = (const float*)d_in[8];
    const float* Wv   = (const float*)d_in[9];
    const float* bv   = (const float*)d_in[10];
    const float* Wa   = (const float*)d_in[11];
    const float* ba   = (const float*)d_in[12];
    const float* skip = (const float*)d_in[13];
    const float* arel = (const float*)d_in[14];
    const float* mrel = (const float*)d_in[15];
    const float* prel = (const float*)d_in[16];

    const int NA = in_sizes[0] / F;
    const int NB = in_sizes[1] / F;
    const int E0 = in_sizes[2] / 2, E1 = in_sizes[3] / 2, E2 = in_sizes[4] / 2;
    const int ET = E0 + E1 + E2;
    const int NT = NB + NA + NA;   // combined dst space: e0 | e1 | e2

    float* ws = (float*)d_ws;
    size_t o = 0;
    float* x1af  = ws + o; o += (size_t)NA * F;    // layer-1 out f32 (residual path)
    float* x1bf  = ws + o; o += (size_t)NB * F;
    float* bslots= ws + o; o += 2 * 10 * 128;
    // ints
    int* iws = (int*)(ws + o);
    size_t io = 0;
    int* cnt   = iws + io; io += NT;
    int* bsum  = iws + io; io += 1024;
    int* offc  = iws + io; io += NT + 1;
    int* woff  = iws + io; io += NT;
    int* csrS  = iws + io; io += ET;
    io = (io + 7) & ~(size_t)7;
    // shorts (bf16)
    short* sws = (short*)(iws + io);
    size_t so = 0;
    short* bufA  = sws + so; so += (size_t)5 * NA * F;   // q0,k0,v0,k2,v2
    short* bufB  = sws + so; so += (size_t)3 * NB * F;   // q1,k1,v1
    short* aggA  = sws + so; so += (size_t)NA * F;
    short* aggB  = sws + so; so += (size_t)NB * F;
    short* x1ab  = sws + so; so += (size_t)NA * F;       // layer-1 out bf16 (GEMM path)
    short* x1bb  = sws + so; so += (size_t)NB * F;
    short* Wslots= sws + so; so += (size_t)2 * 10 * 16384;

    float* outA = (float*)d_out;
    float* outB = (float*)d_out + (size_t)NA * F;

    // ---- weights for both layers (activation-independent) ----
    {
        dim3 g(cdiv(10 * 16384 + 10 * 128, 256), 2);
        prep_weights<<<g, 256, 0, stream>>>(Wk, bk, Wq, bq, Wv, bv, Wa, ba,
                                            arel, mrel, Wslots, bslots);
    }

    // ---- combined CSR (6 dispatches) ----
    hipMemsetAsync(cnt, 0, (size_t)NT * sizeof(int), stream);
    hist_all<<<cdiv(ET, 256), 256, 0, stream>>>(ei_ab, ei_ba, ei_aa, E0, E1, E2, NB, NA, cnt);
    {
        int nb = cdiv(NT, 256);
        scan1<<<nb, 256, 0, stream>>>(cnt, NT, offc, bsum);
        scan2<<<1, 1024, 0, stream>>>(bsum, nb, offc + NT);
        scan3<<<nb, 256, 0, stream>>>(offc, woff, bsum, NT);
    }
    scatter_all<<<cdiv(ET, 256), 256, 0, stream>>>(ei_ab, ei_ba, ei_aa, E0, E1, E2, NB, NA, woff, csrS);

    const int* off_e0 = offc;
    const int* off_e1 = offc + NB;
    const int* off_e2 = offc + NB + NA;

    for (int l = 0; l < 2; ++l) {
        const short* Wl = Wslots + (size_t)l * 10 * 16384;
        const float* bl = bslots + (size_t)l * 10 * 128;

        // x0-group: q0,k0,v0,k2,v2 ; x1-group: q1,k1,v1
        if (l == 0) {
            dim3 g0(cdiv(NA, 64), 5);
            gemm_qkv<float><<<g0, 256, 0, stream>>>(xa, Wl, bl, bufA, NA);
            dim3 g1(cdiv(NB, 64), 3);
            gemm_qkv<float><<<g1, 256, 0, stream>>>(xb, Wl + (size_t)5 * 16384, bl + 5 * 128, bufB, NB);
        } else {
            dim3 g0(cdiv(NA, 64), 5);
            gemm_qkv<short><<<g0, 256, 0, stream>>>(x1ab, Wl, bl, bufA, NA);
            dim3 g1(cdiv(NB, 64), 3);
            gemm_qkv<short><<<g1, 256, 0, stream>>>(x1bb, Wl + (size_t)5 * 16384, bl + 5 * 128, bufB, NB);
        }

        const short* q0 = bufA;
        const short* k0 = bufA + (size_t)1 * NA * F;
        const short* v0 = bufA + (size_t)2 * NA * F;
        const short* k2 = bufA + (size_t)3 * NA * F;
        const short* v2 = bufA + (size_t)4 * NA * F;
        const short* q1 = bufB;
        const short* k1 = bufB + (size_t)1 * NB * F;
        const short* v1 = bufB + (size_t)2 * NB * F;

        // dst type b: e0 only
        seg_attn2<1><<<cdiv(NB, 4), 256, 0, stream>>>(
            q1, k0, v0, off_e0, nullptr, nullptr, nullptr, csrS,
            prel + (size_t)(l * 3 + 0) * NH, nullptr, aggB, NB);
        // dst type a: e1 + e2
        seg_attn2<2><<<cdiv(NA, 4), 256, 0, stream>>>(
            q0, k1, v1, off_e1, k2, v2, off_e2, csrS,
            prel + (size_t)(l * 3 + 1) * NH, prel + (size_t)(l * 3 + 2) * NH, aggA, NA);

        if (l == 0) {
            gemm_out<1><<<cdiv(NA, 64), 256, 0, stream>>>(aggA, Wl + (size_t)8 * 16384,
                bl + 8 * 128, xa, skip + 0, x1af, x1ab, NA);
            gemm_out<1><<<cdiv(NB, 64), 256, 0, stream>>>(aggB, Wl + (size_t)9 * 16384,
                bl + 9 * 128, xb, skip + 1, x1bf, x1bb, NB);
        } else {
            gemm_out<0><<<cdiv(NA, 64), 256, 0, stream>>>(aggA, Wl + (size_t)8 * 16384,
                bl + 8 * 128, x1af, skip + 2, outA, nullptr, NA);
            gemm_out<0><<<cdiv(NB, 64), 256, 0, stream>>>(aggB, Wl + (size_t)9 * 16384,
                bl + 9 * 128, x1bf, skip + 3, outB, nullptr, NB);
        }
    }
}

// Round 6
// 456.911 us; speedup vs baseline: 22.3550x; 1.2076x over previous
//
#include <hip/hip_runtime.h>
#include <hip/hip_bf16.h>
#include <math.h>

#define F 128
#define NH 8
#define HD 16

static inline int cdiv(int a, int b) { return (a + b - 1) / b; }

typedef __attribute__((ext_vector_type(8))) short bf16x8;
typedef __attribute__((ext_vector_type(4))) float f32x4;

__device__ __forceinline__ float geluf(float x) {
    return 0.5f * x * (1.f + erff(x * 0.70710678118654752440f));
}

__device__ __forceinline__ short f2bf(float f) {
    __hip_bfloat16 h = __float2bfloat16(f);
    return *reinterpret_cast<short*>(&h);
}

__device__ __forceinline__ float bflo(unsigned int u) { return __uint_as_float(u << 16); }
__device__ __forceinline__ float bfhi(unsigned int u) { return __uint_as_float(u & 0xffff0000u); }
__device__ __forceinline__ float bf2f(short s) {
    return __uint_as_float(((unsigned int)(unsigned short)s) << 16);
}

// ---- weight prep: per layer 10 slots of bf16 [n][k] + 10 f32 bias slots ----
// slot: 0 q(t0) | 1 k-fused e0 | 2 v-fused e0 | 3 k-fused e2 | 4 v-fused e2
//       5 q(t1) | 6 k-fused e1 | 7 v-fused e1 | 8 a(t0) | 9 a(t1)
__device__ __forceinline__ void slot_info(int slot, int& kind, int& wsel, int& e, int& t) {
    switch (slot) {
        case 0: kind = 0; wsel = 0; t = 0; e = 0; break;
        case 1: kind = 1; wsel = 1; t = 0; e = 0; break;
        case 2: kind = 1; wsel = 2; t = 0; e = 0; break;
        case 3: kind = 1; wsel = 1; t = 0; e = 2; break;
        case 4: kind = 1; wsel = 2; t = 0; e = 2; break;
        case 5: kind = 0; wsel = 0; t = 1; e = 0; break;
        case 6: kind = 1; wsel = 1; t = 1; e = 1; break;
        case 7: kind = 1; wsel = 2; t = 1; e = 1; break;
        case 8: kind = 0; wsel = 3; t = 0; e = 0; break;
        default: kind = 0; wsel = 3; t = 1; e = 0; break;
    }
}

__global__ void prep_weights(const float* __restrict__ Wk, const float* __restrict__ bk,
                             const float* __restrict__ Wq, const float* __restrict__ bq,
                             const float* __restrict__ Wv, const float* __restrict__ bv,
                             const float* __restrict__ Wa, const float* __restrict__ ba,
                             const float* __restrict__ arel, const float* __restrict__ mrel,
                             short* __restrict__ Wslots, float* __restrict__ bslots) {
    const int WTOT = 10 * 16384;
    const int layer = blockIdx.y;
    short* Wl = Wslots + (size_t)layer * WTOT;
    float* bl = bslots + (size_t)layer * 10 * 128;
    int idx = blockIdx.x * blockDim.x + threadIdx.x;
    if (idx < WTOT) {
        int slot = idx >> 14, rem = idx & 16383;
        int n = rem >> 7, k = rem & 127;
        int kind, wsel, e, t;
        slot_info(slot, kind, wsel, e, t);
        float out;
        if (kind == 0) {
            const float* Wb = (wsel == 0 ? Wq : Wa) + (size_t)(layer * 2 + t) * 16384;
            out = Wb[k * 128 + n];
        } else {
            int h = n >> 4, j = n & 15;
            const float* Wb = (wsel == 1 ? Wk : Wv) + (size_t)(layer * 2 + t) * 16384;
            const float* R = (wsel == 1 ? arel : mrel) + (size_t)((layer * 3 + e) * NH + h) * 256;
            float s = 0.f;
            #pragma unroll
            for (int d = 0; d < HD; ++d) s += Wb[k * 128 + h * 16 + d] * R[d * 16 + j];
            out = s;
        }
        Wl[(size_t)slot * 16384 + n * 128 + k] = f2bf(out);
    } else {
        int r = idx - WTOT;
        if (r < 10 * 128) {
            int slot = r >> 7, n = r & 127;
            int kind, wsel, e, t;
            slot_info(slot, kind, wsel, e, t);
            float out;
            if (kind == 0) {
                const float* bb = (wsel == 0 ? bq : ba) + (size_t)(layer * 2 + t) * 128;
                out = bb[n];
            } else {
                int h = n >> 4, j = n & 15;
                const float* bb = (wsel == 1 ? bk : bv) + (size_t)(layer * 2 + t) * 128;
                const float* R = (wsel == 1 ? arel : mrel) + (size_t)((layer * 3 + e) * NH + h) * 256;
                float s = 0.f;
                #pragma unroll
                for (int d = 0; d < HD; ++d) s += bb[h * 16 + d] * R[d * 16 + j];
                out = s;
            }
            bl[slot * 128 + n] = out;
        }
    }
}

// ---- slot-looped MFMA GEMM, merged A/B sides ------------------------------
// Block stages its 64 A-rows ONCE (registers hold A-fragments), then loops
// over S weight slots: stage W -> MFMA -> store bf16.
template <typename AT>
__global__ __launch_bounds__(256) void gemm_qkv_all(
    const AT* __restrict__ Aa, const AT* __restrict__ Ab,
    const short* __restrict__ Wl, const float* __restrict__ bl,
    short* __restrict__ bufA, short* __restrict__ bufB,
    int NA_, int NB_, int nbA) {
    __shared__ short Ws[128 * 136];
    __shared__ short As[64 * 136];
    const int tid = threadIdx.x;
    const int bid = blockIdx.x;
    const int side = bid >= nbA;
    const AT* A = side ? Ab : Aa;
    const int N = side ? NB_ : NA_;
    const int row0 = (side ? bid - nbA : bid) * 64;
    const short* Wbase = Wl + (side ? (size_t)5 * 16384 : 0);
    const float* bbase = bl + (side ? 5 * 128 : 0);
    short* obase = side ? bufB : bufA;
    const int S = side ? 3 : 5;

    #pragma unroll
    for (int it = 0; it < 4; ++it) {
        int chunk = tid + it * 256;
        int r = chunk >> 4, c8 = (chunk & 15) * 8;
        int gr = row0 + r;
        bf16x8 s = {};
        if (gr < N) {
            if constexpr (sizeof(AT) == 4) {
                float4 v0 = *(const float4*)&A[(size_t)gr * F + c8];
                float4 v1 = *(const float4*)&A[(size_t)gr * F + c8 + 4];
                s[0] = f2bf(v0.x); s[1] = f2bf(v0.y); s[2] = f2bf(v0.z); s[3] = f2bf(v0.w);
                s[4] = f2bf(v1.x); s[5] = f2bf(v1.y); s[6] = f2bf(v1.z); s[7] = f2bf(v1.w);
            } else {
                s = *(const bf16x8*)&A[(size_t)gr * F + c8];
            }
        }
        *(bf16x8*)&As[r * 136 + c8] = s;
    }
    __syncthreads();

    const int wave = tid >> 6;
    const int lane = tid & 63;
    const int m16 = lane & 15;
    const int kg = lane >> 4;
    const int arow = wave * 16 + m16;

    bf16x8 af[4];
    #pragma unroll
    for (int kq = 0; kq < 4; ++kq)
        af[kq] = *(const bf16x8*)&As[arow * 136 + kq * 32 + kg * 8];

    for (int s = 0; s < S; ++s) {
        if (s) __syncthreads();   // all waves done reading Ws of previous slot
        const short* Wt = Wbase + (size_t)s * 16384;
        #pragma unroll
        for (int it = 0; it < 8; ++it) {
            int chunk = tid + it * 256;
            int r = chunk >> 4, c8 = (chunk & 15) * 8;
            *(int4*)&Ws[r * 136 + c8] = *(const int4*)&Wt[r * 128 + c8];
        }
        __syncthreads();

        f32x4 acc[8] = {};
        #pragma unroll
        for (int kq = 0; kq < 4; ++kq) {
            #pragma unroll
            for (int nt = 0; nt < 8; ++nt) {
                bf16x8 b = *(const bf16x8*)&Ws[(nt * 16 + m16) * 136 + kq * 32 + kg * 8];
                acc[nt] = __builtin_amdgcn_mfma_f32_16x16x32_bf16(af[kq], b, acc[nt], 0, 0, 0);
            }
        }

        const float* bias = bbase + s * 128;
        short* C = obase + (size_t)s * (size_t)N * F;
        #pragma unroll
        for (int nt = 0; nt < 8; ++nt) {
            int n = nt * 16 + m16;
            float blv = bias[n];
            #pragma unroll
            for (int r = 0; r < 4; ++r) {
                int gr = row0 + wave * 16 + kg * 4 + r;
                if (gr >= N) continue;
                C[(size_t)gr * F + n] = f2bf(acc[nt][r] + blv);
            }
        }
    }
}

// ---- out-projection, merged sides -----------------------------------------
// OMODE 1 (layer 0): xres f32, out = relu(skip-gate) stored bf16.
// OMODE 0 (layer 1): xres bf16, out stored f32 (final).
template <int OMODE>
__global__ __launch_bounds__(256) void gemm_out_all(
    const short* __restrict__ aggA, const short* __restrict__ aggB,
    const short* __restrict__ Wl, const float* __restrict__ bl,
    const float* __restrict__ xfA, const float* __restrict__ xfB,
    const short* __restrict__ xbA, const short* __restrict__ xbB,
    const float* __restrict__ skipp,
    float* __restrict__ CfA, float* __restrict__ CfB,
    short* __restrict__ CbA, short* __restrict__ CbB,
    int NA_, int NB_, int nbA) {
    __shared__ short Ws[128 * 136];
    __shared__ short As[64 * 136];
    const int tid = threadIdx.x;
    const int bid = blockIdx.x;
    const int side = bid >= nbA;
    const short* A = side ? aggB : aggA;
    const int N = side ? NB_ : NA_;
    const int row0 = (side ? bid - nbA : bid) * 64;
    const short* Wt = Wl + (size_t)(side ? 9 : 8) * 16384;
    const float* bias = bl + (side ? 9 : 8) * 128;

    #pragma unroll
    for (int it = 0; it < 8; ++it) {
        int chunk = tid + it * 256;
        int r = chunk >> 4, c8 = (chunk & 15) * 8;
        *(int4*)&Ws[r * 136 + c8] = *(const int4*)&Wt[r * 128 + c8];
    }
    #pragma unroll
    for (int it = 0; it < 4; ++it) {
        int chunk = tid + it * 256;
        int r = chunk >> 4, c8 = (chunk & 15) * 8;
        int gr = row0 + r;
        bf16x8 s = {};
        if (gr < N) {
            s = *(const bf16x8*)&A[(size_t)gr * F + c8];
            #pragma unroll
            for (int u = 0; u < 8; ++u) s[u] = f2bf(geluf(bf2f(s[u])));
        }
        *(bf16x8*)&As[r * 136 + c8] = s;
    }
    __syncthreads();

    const int wave = tid >> 6;
    const int lane = tid & 63;
    const int m16 = lane & 15;
    const int kg = lane >> 4;
    const int arow = wave * 16 + m16;

    f32x4 acc[8] = {};
    #pragma unroll
    for (int k0 = 0; k0 < 128; k0 += 32) {
        bf16x8 a = *(const bf16x8*)&As[arow * 136 + k0 + kg * 8];
        #pragma unroll
        for (int nt = 0; nt < 8; ++nt) {
            bf16x8 b = *(const bf16x8*)&Ws[(nt * 16 + m16) * 136 + k0 + kg * 8];
            acc[nt] = __builtin_amdgcn_mfma_f32_16x16x32_bf16(a, b, acc[nt], 0, 0, 0);
        }
    }

    float sg = 1.f / (1.f + expf(-skipp[side]));
    #pragma unroll
    for (int nt = 0; nt < 8; ++nt) {
        int n = nt * 16 + m16;
        float blv = bias[n];
        #pragma unroll
        for (int r = 0; r < 4; ++r) {
            int gr = row0 + wave * 16 + kg * 4 + r;
            if (gr >= N) continue;
            float v = acc[nt][r] + blv;
            if (OMODE == 1) {
                float xr = (side ? xfB : xfA)[(size_t)gr * F + n];
                v = sg * v + (1.f - sg) * xr;
                v = fmaxf(v, 0.f);
                (side ? CbB : CbA)[(size_t)gr * F + n] = f2bf(v);
            } else {
                float xr = bf2f((side ? xbB : xbA)[(size_t)gr * F + n]);
                v = sg * v + (1.f - sg) * xr;
                (side ? CfB : CfA)[(size_t)gr * F + n] = v;
            }
        }
    }
}

// ---------------- combined CSR build (all 3 edge types in one pass) ---------

__global__ void hist_all(const int* __restrict__ ei0, const int* __restrict__ ei1,
                         const int* __restrict__ ei2, int E0, int E1, int E2,
                         int NB_, int NA_, int* __restrict__ cnt) {
    int i = blockIdx.x * 256 + threadIdx.x;
    if (i >= E0 + E1 + E2) return;
    const int* ei; int li, Ee, base;
    if (i < E0)           { li = i;           ei = ei0; Ee = E0; base = 0; }
    else if (i < E0 + E1) { li = i - E0;      ei = ei1; Ee = E1; base = NB_; }
    else                  { li = i - E0 - E1; ei = ei2; Ee = E2; base = NB_ + NA_; }
    atomicAdd(&cnt[base + ei[Ee + li]], 1);
}

__global__ void scan1(const int* __restrict__ cnt, int n, int* __restrict__ off,
                      int* __restrict__ bsum) {
    __shared__ int lds[256];
    int tid = threadIdx.x, i = blockIdx.x * 256 + tid;
    int v = (i < n) ? cnt[i] : 0;
    lds[tid] = v;
    __syncthreads();
    #pragma unroll
    for (int s = 1; s < 256; s <<= 1) {
        int t = (tid >= s) ? lds[tid - s] : 0;
        __syncthreads();
        lds[tid] += t;
        __syncthreads();
    }
    if (i < n) off[i] = lds[tid] - v;
    if (tid == 255) bsum[blockIdx.x] = lds[255];
}

__global__ __launch_bounds__(1024) void scan2(int* __restrict__ bsum, int nb,
                                              int* __restrict__ off_n) {
    __shared__ int lds[1024];
    int tid = threadIdx.x;
    int v = (tid < nb) ? bsum[tid] : 0;
    lds[tid] = v;
    __syncthreads();
    #pragma unroll
    for (int s = 1; s < 1024; s <<= 1) {
        int t = (tid >= s) ? lds[tid - s] : 0;
        __syncthreads();
        lds[tid] += t;
        __syncthreads();
    }
    if (tid < nb) bsum[tid] = lds[tid] - v;
    if (tid == 1023) *off_n = lds[1023];
}

__global__ void scan3(int* __restrict__ off, int* __restrict__ woff,
                      const int* __restrict__ bsum, int n) {
    int i = blockIdx.x * 256 + threadIdx.x;
    if (i < n) {
        int v = off[i] + bsum[blockIdx.x];
        off[i] = v;
        woff[i] = v;
    }
}

__global__ void scatter_all(const int* __restrict__ ei0, const int* __restrict__ ei1,
                            const int* __restrict__ ei2, int E0, int E1, int E2,
                            int NB_, int NA_, int* __restrict__ woff,
                            int* __restrict__ csr_src) {
    int i = blockIdx.x * 256 + threadIdx.x;
    if (i >= E0 + E1 + E2) return;
    const int* ei; int li, Ee, base;
    if (i < E0)           { li = i;           ei = ei0; Ee = E0; base = 0; }
    else if (i < E0 + E1) { li = i - E0;      ei = ei1; Ee = E1; base = NB_; }
    else                  { li = i - E0 - E1; ei = ei2; Ee = E2; base = NB_ + NA_; }
    int p = atomicAdd(&woff[base + ei[Ee + li]], 1);
    csr_src[p] = ei[li];
}

// ---- fused segment attention, merged dst types ----------------------------
#define CH 8
template <int NSET>
__device__ __forceinline__ void seg_attn_core(
    const short* __restrict__ q,
    const short* __restrict__ k1, const short* __restrict__ v1,
    const int* __restrict__ off1,
    const short* __restrict__ k2, const short* __restrict__ v2,
    const int* __restrict__ off2,
    const int* __restrict__ csr_src,
    const float* __restrict__ prel1, const float* __restrict__ prel2,
    short* __restrict__ agg, int Nd, int blk) {
    int dst = blk * 4 + (threadIdx.x >> 6);
    if (dst >= Nd) return;
    int l = threadIdx.x & 63;
    int h = l >> 3;
    unsigned int qu = ((const unsigned int*)(q + (size_t)dst * F))[l];
    float qlo = bflo(qu), qhi = bfhi(qu);
    float rlo = 0.f, rhi = 0.f;
    #pragma unroll
    for (int s = 0; s < NSET; ++s) {
        const short* kk = s ? k2 : k1;
        const short* vv = s ? v2 : v1;
        const int* off = s ? off2 : off1;
        float pr = (s ? prel2[h] : prel1[h]) * 0.25f;
        int e0 = off[dst], e1 = off[dst + 1];
        float m = -INFINITY, den = 0.f, alo = 0.f, ahi = 0.f;
        for (int base = e0; base < e1; base += CH) {
            int n = e1 - base; if (n > CH) n = CH;
            int sj[CH];
            unsigned int ku[CH], vu[CH];
            #pragma unroll
            for (int c = 0; c < CH; ++c) if (c < n) sj[c] = csr_src[base + c];
            #pragma unroll
            for (int c = 0; c < CH; ++c) if (c < n) {
                ku[c] = ((const unsigned int*)(kk + (size_t)sj[c] * F))[l];
                vu[c] = ((const unsigned int*)(vv + (size_t)sj[c] * F))[l];
            }
            float al[CH];
            float cmax = -INFINITY;
            #pragma unroll
            for (int c = 0; c < CH; ++c) if (c < n) {
                float p = bflo(ku[c]) * qlo + bfhi(ku[c]) * qhi;
                p += __shfl_xor(p, 4, 8);
                p += __shfl_xor(p, 2, 8);
                p += __shfl_xor(p, 1, 8);
                al[c] = p * pr;
                cmax = fmaxf(cmax, al[c]);
            }
            float nm = fmaxf(m, cmax);
            float corr = __expf(m - nm);
            den *= corr; alo *= corr; ahi *= corr;
            #pragma unroll
            for (int c = 0; c < CH; ++c) if (c < n) {
                float ex = __expf(al[c] - nm);
                den += ex;
                alo = fmaf(ex, bflo(vu[c]), alo);
                ahi = fmaf(ex, bfhi(vu[c]), ahi);
            }
            m = nm;
        }
        float inv = 1.f / (den + 1e-16f);
        rlo = fmaf(alo, inv, rlo);
        rhi = fmaf(ahi, inv, rhi);
    }
    unsigned int plo = (unsigned int)(unsigned short)f2bf(rlo);
    unsigned int phi = (unsigned int)(unsigned short)f2bf(rhi);
    ((unsigned int*)(agg + (size_t)dst * F))[l] = plo | (phi << 16);
}

__global__ __launch_bounds__(256) void seg_attn_all(
    const short* __restrict__ bufA, const short* __restrict__ bufB,
    const int* __restrict__ off0, const int* __restrict__ off1,
    const int* __restrict__ off2, const int* __restrict__ csrS,
    const float* __restrict__ prelL,
    short* __restrict__ aggA, short* __restrict__ aggB,
    int NA_, int NB_, int nba) {
    const short* q0 = bufA;
    const short* k0 = bufA + (size_t)1 * NA_ * F;
    const short* v0 = bufA + (size_t)2 * NA_ * F;
    const short* k2 = bufA + (size_t)3 * NA_ * F;
    const short* v2 = bufA + (size_t)4 * NA_ * F;
    const short* q1 = bufB;
    const short* k1 = bufB + (size_t)1 * NB_ * F;
    const short* v1 = bufB + (size_t)2 * NB_ * F;
    if ((int)blockIdx.x < nba) {
        seg_attn_core<2>(q0, k1, v1, off1, k2, v2, off2, csrS,
                         prelL + 1 * NH, prelL + 2 * NH, aggA, NA_, blockIdx.x);
    } else {
        seg_attn_core<1>(q1, k0, v0, off0, nullptr, nullptr, nullptr, csrS,
                         prelL + 0 * NH, nullptr, aggB, NB_, blockIdx.x - nba);
    }
}

extern "C" void kernel_launch(void* const* d_in, const int* in_sizes, int n_in,
                              void* d_out, int out_size, void* d_ws, size_t ws_size,
                              hipStream_t stream) {
    const float* xa   = (const float*)d_in[0];
    const float* xb   = (const float*)d_in[1];
    const int* ei_ab  = (const int*)d_in[2];
    const int* ei_ba  = (const int*)d_in[3];
    const int* ei_aa  = (const int*)d_in[4];
    const float* Wk   = (const float*)d_in[5];
    const float* bk   = (const float*)d_in[6];
    const float* Wq   = (const float*)d_in[7];
    const float* bq   = (const float*)d_in[8];
    const float* Wv   = (const float*)d_in[9];
    const float* bv   = (const float*)d_in[10];
    const float* Wa   = (const float*)d_in[11];
    const float* ba   = (const float*)d_in[12];
    const float* skip = (const float*)d_in[13];
    const float* arel = (const float*)d_in[14];
    const float* mrel = (const float*)d_in[15];
    const float* prel = (const float*)d_in[16];

    const int NA = in_sizes[0] / F;
    const int NB = in_sizes[1] / F;
    const int E0 = in_sizes[2] / 2, E1 = in_sizes[3] / 2, E2 = in_sizes[4] / 2;
    const int ET = E0 + E1 + E2;
    const int NT = NB + NA + NA;   // combined dst space: e0 | e1 | e2

    float* ws = (float*)d_ws;
    size_t o = 0;
    float* bslots = ws + o; o += 2 * 10 * 128;
    // ints
    int* iws = (int*)(ws + o);
    size_t io = 0;
    int* cnt   = iws + io; io += NT;
    int* bsum  = iws + io; io += 1024;
    int* offc  = iws + io; io += NT + 1;
    int* woff  = iws + io; io += NT;
    int* csrS  = iws + io; io += ET;
    io = (io + 7) & ~(size_t)7;
    // shorts (bf16)
    short* sws = (short*)(iws + io);
    size_t so = 0;
    short* bufA  = sws + so; so += (size_t)5 * NA * F;   // q0,k0,v0,k2,v2
    short* bufB  = sws + so; so += (size_t)3 * NB * F;   // q1,k1,v1
    short* aggA  = sws + so; so += (size_t)NA * F;
    short* aggB  = sws + so; so += (size_t)NB * F;
    short* x1ab  = sws + so; so += (size_t)NA * F;       // layer-1 out, bf16
    short* x1bb  = sws + so; so += (size_t)NB * F;
    short* Wslots= sws + so; so += (size_t)2 * 10 * 16384;

    float* outA = (float*)d_out;
    float* outB = (float*)d_out + (size_t)NA * F;

    // ---- weights for both layers ----
    {
        dim3 g(cdiv(10 * 16384 + 10 * 128, 256), 2);
        prep_weights<<<g, 256, 0, stream>>>(Wk, bk, Wq, bq, Wv, bv, Wa, ba,
                                            arel, mrel, Wslots, bslots);
    }

    // ---- combined CSR ----
    hipMemsetAsync(cnt, 0, (size_t)NT * sizeof(int), stream);
    hist_all<<<cdiv(ET, 256), 256, 0, stream>>>(ei_ab, ei_ba, ei_aa, E0, E1, E2, NB, NA, cnt);
    {
        int nb = cdiv(NT, 256);
        scan1<<<nb, 256, 0, stream>>>(cnt, NT, offc, bsum);
        scan2<<<1, 1024, 0, stream>>>(bsum, nb, offc + NT);
        scan3<<<nb, 256, 0, stream>>>(offc, woff, bsum, NT);
    }
    scatter_all<<<cdiv(ET, 256), 256, 0, stream>>>(ei_ab, ei_ba, ei_aa, E0, E1, E2, NB, NA, woff, csrS);

    const int* off_e0 = offc;
    const int* off_e1 = offc + NB;
    const int* off_e2 = offc + NB + NA;

    const int nbA64 = cdiv(NA, 64), nbB64 = cdiv(NB, 64);
    const int nba4 = cdiv(NA, 4), nbb4 = cdiv(NB, 4);

    for (int l = 0; l < 2; ++l) {
        const short* Wl = Wslots + (size_t)l * 10 * 16384;
        const float* bl = bslots + (size_t)l * 10 * 128;

        if (l == 0) {
            gemm_qkv_all<float><<<nbA64 + nbB64, 256, 0, stream>>>(
                xa, xb, Wl, bl, bufA, bufB, NA, NB, nbA64);
        } else {
            gemm_qkv_all<short><<<nbA64 + nbB64, 256, 0, stream>>>(
                x1ab, x1bb, Wl, bl, bufA, bufB, NA, NB, nbA64);
        }

        seg_attn_all<<<nba4 + nbb4, 256, 0, stream>>>(
            bufA, bufB, off_e0, off_e1, off_e2, csrS,
            prel + (size_t)l * 3 * NH, aggA, aggB, NA, NB, nba4);

        if (l == 0) {
            gemm_out_all<1><<<nbA64 + nbB64, 256, 0, stream>>>(
                aggA, aggB, Wl, bl, xa, xb, nullptr, nullptr,
                skip + 0, nullptr, nullptr, x1ab, x1bb, NA, NB, nbA64);
        } else {
            gemm_out_all<0><<<nbA64 + nbB64, 256, 0, stream>>>(
                aggA, aggB, Wl, bl, nullptr, nullptr, x1ab, x1bb,
                skip + 2, outA, outB, nullptr, nullptr, NA, NB, nbA64);
        }
    }
}

// Round 7
// 381.890 us; speedup vs baseline: 26.7466x; 1.1964x over previous
//
#include <hip/hip_runtime.h>
#include <hip/hip_bf16.h>
#include <math.h>

#define F 128
#define NH 8
#define HD 16

static inline int cdiv(int a, int b) { return (a + b - 1) / b; }

typedef __attribute__((ext_vector_type(8))) short bf16x8;
typedef __attribute__((ext_vector_type(4))) float f32x4;

__device__ __forceinline__ float geluf(float x) {
    return 0.5f * x * (1.f + erff(x * 0.70710678118654752440f));
}

__device__ __forceinline__ short f2bf(float f) {
    __hip_bfloat16 h = __float2bfloat16(f);
    return *reinterpret_cast<short*>(&h);
}

__device__ __forceinline__ float bflo(unsigned int u) { return __uint_as_float(u << 16); }
__device__ __forceinline__ float bfhi(unsigned int u) { return __uint_as_float(u & 0xffff0000u); }
__device__ __forceinline__ float bf2f(short s) {
    return __uint_as_float(((unsigned int)(unsigned short)s) << 16);
}

// ---- weight prep: per layer 10 slots of bf16 [n][k] + 10 f32 bias slots ----
// slot: 0 q(t0) | 1 k-fused e0 | 2 v-fused e0 | 3 k-fused e2 | 4 v-fused e2
//       5 q(t1) | 6 k-fused e1 | 7 v-fused e1 | 8 a(t0) | 9 a(t1)
__device__ __forceinline__ void slot_info(int slot, int& kind, int& wsel, int& e, int& t) {
    switch (slot) {
        case 0: kind = 0; wsel = 0; t = 0; e = 0; break;
        case 1: kind = 1; wsel = 1; t = 0; e = 0; break;
        case 2: kind = 1; wsel = 2; t = 0; e = 0; break;
        case 3: kind = 1; wsel = 1; t = 0; e = 2; break;
        case 4: kind = 1; wsel = 2; t = 0; e = 2; break;
        case 5: kind = 0; wsel = 0; t = 1; e = 0; break;
        case 6: kind = 1; wsel = 1; t = 1; e = 1; break;
        case 7: kind = 1; wsel = 2; t = 1; e = 1; break;
        case 8: kind = 0; wsel = 3; t = 0; e = 0; break;
        default: kind = 0; wsel = 3; t = 1; e = 0; break;
    }
}

__global__ void prep_weights(const float* __restrict__ Wk, const float* __restrict__ bk,
                             const float* __restrict__ Wq, const float* __restrict__ bq,
                             const float* __restrict__ Wv, const float* __restrict__ bv,
                             const float* __restrict__ Wa, const float* __restrict__ ba,
                             const float* __restrict__ arel, const float* __restrict__ mrel,
                             short* __restrict__ Wslots, float* __restrict__ bslots) {
    const int WTOT = 10 * 16384;
    const int layer = blockIdx.y;
    short* Wl = Wslots + (size_t)layer * WTOT;
    float* bl = bslots + (size_t)layer * 10 * 128;
    int idx = blockIdx.x * blockDim.x + threadIdx.x;
    if (idx < WTOT) {
        int slot = idx >> 14, rem = idx & 16383;
        int n = rem >> 7, k = rem & 127;
        int kind, wsel, e, t;
        slot_info(slot, kind, wsel, e, t);
        float out;
        if (kind == 0) {
            const float* Wb = (wsel == 0 ? Wq : Wa) + (size_t)(layer * 2 + t) * 16384;
            out = Wb[k * 128 + n];
        } else {
            int h = n >> 4, j = n & 15;
            const float* Wb = (wsel == 1 ? Wk : Wv) + (size_t)(layer * 2 + t) * 16384;
            const float* R = (wsel == 1 ? arel : mrel) + (size_t)((layer * 3 + e) * NH + h) * 256;
            float s = 0.f;
            #pragma unroll
            for (int d = 0; d < HD; ++d) s += Wb[k * 128 + h * 16 + d] * R[d * 16 + j];
            out = s;
        }
        Wl[(size_t)slot * 16384 + n * 128 + k] = f2bf(out);
    } else {
        int r = idx - WTOT;
        if (r < 10 * 128) {
            int slot = r >> 7, n = r & 127;
            int kind, wsel, e, t;
            slot_info(slot, kind, wsel, e, t);
            float out;
            if (kind == 0) {
                const float* bb = (wsel == 0 ? bq : ba) + (size_t)(layer * 2 + t) * 128;
                out = bb[n];
            } else {
                int h = n >> 4, j = n & 15;
                const float* bb = (wsel == 1 ? bk : bv) + (size_t)(layer * 2 + t) * 128;
                const float* R = (wsel == 1 ? arel : mrel) + (size_t)((layer * 3 + e) * NH + h) * 256;
                float s = 0.f;
                #pragma unroll
                for (int d = 0; d < HD; ++d) s += bb[h * 16 + d] * R[d * 16 + j];
                out = s;
            }
            bl[slot * 128 + n] = out;
        }
    }
}

// ---- slot-looped MFMA GEMM, merged A/B sides, LDS-staged vector stores ----
// Outputs: q -> [N][128] bf16; k/v pairs -> interleaved kv [N][256] bf16.
template <typename AT>
__global__ __launch_bounds__(256) void gemm_qkv_all(
    const AT* __restrict__ Aa, const AT* __restrict__ Ab,
    const short* __restrict__ Wl, const float* __restrict__ bl,
    short* __restrict__ qA, short* __restrict__ kvA0, short* __restrict__ kvA2,
    short* __restrict__ qB, short* __restrict__ kvB1,
    int NA_, int NB_, int nbA) {
    __shared__ short Ws[128 * 136];
    __shared__ short As[64 * 136];
    float* Wsf = (float*)Ws;           // reused as [64][132] f32 output staging
    const int tid = threadIdx.x;
    const int bid = blockIdx.x;
    const int side = bid >= nbA;
    const AT* A = side ? Ab : Aa;
    const int N = side ? NB_ : NA_;
    const int row0 = (side ? bid - nbA : bid) * 64;
    const short* Wbase = Wl + (side ? (size_t)5 * 16384 : 0);
    const float* bbase = bl + (side ? 5 * 128 : 0);
    const int S = side ? 3 : 5;

    #pragma unroll
    for (int it = 0; it < 4; ++it) {
        int chunk = tid + it * 256;
        int r = chunk >> 4, c8 = (chunk & 15) * 8;
        int gr = row0 + r;
        bf16x8 s = {};
        if (gr < N) {
            if constexpr (sizeof(AT) == 4) {
                float4 v0 = *(const float4*)&A[(size_t)gr * F + c8];
                float4 v1 = *(const float4*)&A[(size_t)gr * F + c8 + 4];
                s[0] = f2bf(v0.x); s[1] = f2bf(v0.y); s[2] = f2bf(v0.z); s[3] = f2bf(v0.w);
                s[4] = f2bf(v1.x); s[5] = f2bf(v1.y); s[6] = f2bf(v1.z); s[7] = f2bf(v1.w);
            } else {
                s = *(const bf16x8*)&A[(size_t)gr * F + c8];
            }
        }
        *(bf16x8*)&As[r * 136 + c8] = s;
    }
    __syncthreads();

    const int wave = tid >> 6;
    const int lane = tid & 63;
    const int m16 = lane & 15;
    const int kg = lane >> 4;
    const int arow = wave * 16 + m16;

    bf16x8 af[4];
    #pragma unroll
    for (int kq = 0; kq < 4; ++kq)
        af[kq] = *(const bf16x8*)&As[arow * 136 + kq * 32 + kg * 8];

    for (int s = 0; s < S; ++s) {
        if (s) __syncthreads();
        const short* Wt = Wbase + (size_t)s * 16384;
        #pragma unroll
        for (int it = 0; it < 8; ++it) {
            int chunk = tid + it * 256;
            int r = chunk >> 4, c8 = (chunk & 15) * 8;
            *(int4*)&Ws[r * 136 + c8] = *(const int4*)&Wt[r * 128 + c8];
        }
        __syncthreads();

        f32x4 acc[8] = {};
        #pragma unroll
        for (int kq = 0; kq < 4; ++kq) {
            #pragma unroll
            for (int nt = 0; nt < 8; ++nt) {
                bf16x8 b = *(const bf16x8*)&Ws[(nt * 16 + m16) * 136 + kq * 32 + kg * 8];
                acc[nt] = __builtin_amdgcn_mfma_f32_16x16x32_bf16(af[kq], b, acc[nt], 0, 0, 0);
            }
        }
        __syncthreads();   // all Ws reads (MFMA operands) done before overwrite

        #pragma unroll
        for (int nt = 0; nt < 8; ++nt)
            #pragma unroll
            for (int r = 0; r < 4; ++r)
                Wsf[(wave * 16 + kg * 4 + r) * 132 + nt * 16 + m16] = acc[nt][r];
        __syncthreads();

        // slot -> (dst ptr, ld, col offset)
        short* optr; int old, ooff;
        if (side) {
            if (s == 0)      { optr = qB;   old = 128; ooff = 0; }
            else if (s == 1) { optr = kvB1; old = 256; ooff = 0; }
            else             { optr = kvB1; old = 256; ooff = 128; }
        } else {
            if (s == 0)      { optr = qA;   old = 128; ooff = 0; }
            else if (s == 1) { optr = kvA0; old = 256; ooff = 0; }
            else if (s == 2) { optr = kvA0; old = 256; ooff = 128; }
            else if (s == 3) { optr = kvA2; old = 256; ooff = 0; }
            else             { optr = kvA2; old = 256; ooff = 128; }
        }
        const float* bias = bbase + s * 128;
        #pragma unroll
        for (int it = 0; it < 4; ++it) {
            int chunk = tid + it * 256;
            int r = chunk >> 4, c8 = (chunk & 15) * 8;
            int gr = row0 + r;
            if (gr >= N) continue;
            float4 b0 = *(const float4*)&bias[c8];
            float4 b1 = *(const float4*)&bias[c8 + 4];
            bf16x8 o;
            o[0] = f2bf(Wsf[r * 132 + c8 + 0] + b0.x);
            o[1] = f2bf(Wsf[r * 132 + c8 + 1] + b0.y);
            o[2] = f2bf(Wsf[r * 132 + c8 + 2] + b0.z);
            o[3] = f2bf(Wsf[r * 132 + c8 + 3] + b0.w);
            o[4] = f2bf(Wsf[r * 132 + c8 + 4] + b1.x);
            o[5] = f2bf(Wsf[r * 132 + c8 + 5] + b1.y);
            o[6] = f2bf(Wsf[r * 132 + c8 + 6] + b1.z);
            o[7] = f2bf(Wsf[r * 132 + c8 + 7] + b1.w);
            *(bf16x8*)&optr[(size_t)gr * old + ooff + c8] = o;
        }
    }
}

// ---- out-projection, merged sides, LDS-staged vector stores ---------------
// OMODE 1 (layer 0): xres f32, out = relu(skip-gate) stored bf16.
// OMODE 0 (layer 1): xres bf16, out stored f32 (final).
template <int OMODE>
__global__ __launch_bounds__(256) void gemm_out_all(
    const short* __restrict__ aggA, const short* __restrict__ aggB,
    const short* __restrict__ Wl, const float* __restrict__ bl,
    const float* __restrict__ xfA, const float* __restrict__ xfB,
    const short* __restrict__ xbA, const short* __restrict__ xbB,
    const float* __restrict__ skipp,
    float* __restrict__ CfA, float* __restrict__ CfB,
    short* __restrict__ CbA, short* __restrict__ CbB,
    int NA_, int NB_, int nbA) {
    __shared__ short Ws[128 * 136];
    __shared__ short As[64 * 136];
    float* Wsf = (float*)Ws;
    const int tid = threadIdx.x;
    const int bid = blockIdx.x;
    const int side = bid >= nbA;
    const short* A = side ? aggB : aggA;
    const int N = side ? NB_ : NA_;
    const int row0 = (side ? bid - nbA : bid) * 64;
    const short* Wt = Wl + (size_t)(side ? 9 : 8) * 16384;
    const float* bias = bl + (side ? 9 : 8) * 128;

    #pragma unroll
    for (int it = 0; it < 8; ++it) {
        int chunk = tid + it * 256;
        int r = chunk >> 4, c8 = (chunk & 15) * 8;
        *(int4*)&Ws[r * 136 + c8] = *(const int4*)&Wt[r * 128 + c8];
    }
    #pragma unroll
    for (int it = 0; it < 4; ++it) {
        int chunk = tid + it * 256;
        int r = chunk >> 4, c8 = (chunk & 15) * 8;
        int gr = row0 + r;
        bf16x8 s = {};
        if (gr < N) {
            s = *(const bf16x8*)&A[(size_t)gr * F + c8];
            #pragma unroll
            for (int u = 0; u < 8; ++u) s[u] = f2bf(geluf(bf2f(s[u])));
        }
        *(bf16x8*)&As[r * 136 + c8] = s;
    }
    __syncthreads();

    const int wave = tid >> 6;
    const int lane = tid & 63;
    const int m16 = lane & 15;
    const int kg = lane >> 4;
    const int arow = wave * 16 + m16;

    f32x4 acc[8] = {};
    #pragma unroll
    for (int k0 = 0; k0 < 128; k0 += 32) {
        bf16x8 a = *(const bf16x8*)&As[arow * 136 + k0 + kg * 8];
        #pragma unroll
        for (int nt = 0; nt < 8; ++nt) {
            bf16x8 b = *(const bf16x8*)&Ws[(nt * 16 + m16) * 136 + k0 + kg * 8];
            acc[nt] = __builtin_amdgcn_mfma_f32_16x16x32_bf16(a, b, acc[nt], 0, 0, 0);
        }
    }
    __syncthreads();

    #pragma unroll
    for (int nt = 0; nt < 8; ++nt)
        #pragma unroll
        for (int r = 0; r < 4; ++r)
            Wsf[(wave * 16 + kg * 4 + r) * 132 + nt * 16 + m16] = acc[nt][r];
    __syncthreads();

    float sg = 1.f / (1.f + expf(-skipp[side]));
    #pragma unroll
    for (int it = 0; it < 4; ++it) {
        int chunk = tid + it * 256;
        int r = chunk >> 4, c8 = (chunk & 15) * 8;
        int gr = row0 + r;
        if (gr >= N) continue;
        float4 b0 = *(const float4*)&bias[c8];
        float4 b1 = *(const float4*)&bias[c8 + 4];
        float v[8];
        #pragma unroll
        for (int u = 0; u < 8; ++u) v[u] = Wsf[r * 132 + c8 + u];
        v[0] += b0.x; v[1] += b0.y; v[2] += b0.z; v[3] += b0.w;
        v[4] += b1.x; v[5] += b1.y; v[6] += b1.z; v[7] += b1.w;
        if (OMODE == 1) {
            const float* xf = side ? xfB : xfA;
            float4 x0 = *(const float4*)&xf[(size_t)gr * F + c8];
            float4 x1 = *(const float4*)&xf[(size_t)gr * F + c8 + 4];
            float xr[8] = {x0.x, x0.y, x0.z, x0.w, x1.x, x1.y, x1.z, x1.w};
            bf16x8 o;
            #pragma unroll
            for (int u = 0; u < 8; ++u)
                o[u] = f2bf(fmaxf(sg * v[u] + (1.f - sg) * xr[u], 0.f));
            *(bf16x8*)&(side ? CbB : CbA)[(size_t)gr * F + c8] = o;
        } else {
            const short* xb = side ? xbB : xbA;
            bf16x8 xrv = *(const bf16x8*)&xb[(size_t)gr * F + c8];
            float* Cf = side ? CfB : CfA;
            float o[8];
            #pragma unroll
            for (int u = 0; u < 8; ++u)
                o[u] = sg * v[u] + (1.f - sg) * bf2f(xrv[u]);
            *(float4*)&Cf[(size_t)gr * F + c8]     = make_float4(o[0], o[1], o[2], o[3]);
            *(float4*)&Cf[(size_t)gr * F + c8 + 4] = make_float4(o[4], o[5], o[6], o[7]);
        }
    }
}

// ---------------- combined CSR build (all 3 edge types in one pass) ---------

__global__ void hist_all(const int* __restrict__ ei0, const int* __restrict__ ei1,
                         const int* __restrict__ ei2, int E0, int E1, int E2,
                         int NB_, int NA_, int* __restrict__ cnt) {
    int i = blockIdx.x * 256 + threadIdx.x;
    if (i >= E0 + E1 + E2) return;
    const int* ei; int li, Ee, base;
    if (i < E0)           { li = i;           ei = ei0; Ee = E0; base = 0; }
    else if (i < E0 + E1) { li = i - E0;      ei = ei1; Ee = E1; base = NB_; }
    else                  { li = i - E0 - E1; ei = ei2; Ee = E2; base = NB_ + NA_; }
    atomicAdd(&cnt[base + ei[Ee + li]], 1);
}

__global__ void scan1(const int* __restrict__ cnt, int n, int* __restrict__ off,
                      int* __restrict__ bsum) {
    __shared__ int lds[256];
    int tid = threadIdx.x, i = blockIdx.x * 256 + tid;
    int v = (i < n) ? cnt[i] : 0;
    lds[tid] = v;
    __syncthreads();
    #pragma unroll
    for (int s = 1; s < 256; s <<= 1) {
        int t = (tid >= s) ? lds[tid - s] : 0;
        __syncthreads();
        lds[tid] += t;
        __syncthreads();
    }
    if (i < n) off[i] = lds[tid] - v;
    if (tid == 255) bsum[blockIdx.x] = lds[255];
}

__global__ __launch_bounds__(1024) void scan2(int* __restrict__ bsum, int nb,
                                              int* __restrict__ off_n) {
    __shared__ int lds[1024];
    int tid = threadIdx.x;
    int v = (tid < nb) ? bsum[tid] : 0;
    lds[tid] = v;
    __syncthreads();
    #pragma unroll
    for (int s = 1; s < 1024; s <<= 1) {
        int t = (tid >= s) ? lds[tid - s] : 0;
        __syncthreads();
        lds[tid] += t;
        __syncthreads();
    }
    if (tid < nb) bsum[tid] = lds[tid] - v;
    if (tid == 1023) *off_n = lds[1023];
}

__global__ void scan3(int* __restrict__ off, int* __restrict__ woff,
                      const int* __restrict__ bsum, int n) {
    int i = blockIdx.x * 256 + threadIdx.x;
    if (i < n) {
        int v = off[i] + bsum[blockIdx.x];
        off[i] = v;
        woff[i] = v;
    }
}

// stores PRE-SCALED src offsets (src * 128 = uint index of the kv row)
__global__ void scatter_all(const int* __restrict__ ei0, const int* __restrict__ ei1,
                            const int* __restrict__ ei2, int E0, int E1, int E2,
                            int NB_, int NA_, int* __restrict__ woff,
                            int* __restrict__ csr_src) {
    int i = blockIdx.x * 256 + threadIdx.x;
    if (i >= E0 + E1 + E2) return;
    const int* ei; int li, Ee, base;
    if (i < E0)           { li = i;           ei = ei0; Ee = E0; base = 0; }
    else if (i < E0 + E1) { li = i - E0;      ei = ei1; Ee = E1; base = NB_; }
    else                  { li = i - E0 - E1; ei = ei2; Ee = E2; base = NB_ + NA_; }
    int p = atomicAdd(&woff[base + ei[Ee + li]], 1);
    csr_src[p] = ei[li] * 128;
}

// ---- fused segment attention over interleaved KV, full/tail chunk split ----
#define CH 8
template <int NSET>
__device__ __forceinline__ void seg_attn_core(
    const unsigned int* __restrict__ q32,
    const unsigned int* __restrict__ kv1, const int* __restrict__ off1,
    const unsigned int* __restrict__ kv2, const int* __restrict__ off2,
    const int* __restrict__ csr_src,
    const float* __restrict__ prel1, const float* __restrict__ prel2,
    unsigned int* __restrict__ agg32, int Nd, int blk) {
    int dst = blk * 4 + (threadIdx.x >> 6);
    if (dst >= Nd) return;
    int l = threadIdx.x & 63;
    int h = l >> 3;
    unsigned int qu = q32[(size_t)dst * 64 + l];
    float qlo = bflo(qu), qhi = bfhi(qu);
    float rlo = 0.f, rhi = 0.f;
    #pragma unroll
    for (int s = 0; s < NSET; ++s) {
        const unsigned int* kv = s ? kv2 : kv1;
        const int* off = s ? off2 : off1;
        float pr = (s ? prel2[h] : prel1[h]) * 0.25f;
        int e0 = off[dst], e1 = off[dst + 1];
        float m = -INFINITY, den = 0.f, alo = 0.f, ahi = 0.f;
        for (int base = e0; base < e1; base += CH) {
            int n = e1 - base; if (n > CH) n = CH;
            float al[CH];
            unsigned int vu[CH];
            float cmax = -INFINITY;
            if (n == CH) {                 // wave-uniform fast path, unmasked
                int sj[CH];
                unsigned int ku[CH];
                #pragma unroll
                for (int c = 0; c < CH; ++c) sj[c] = csr_src[base + c];
                #pragma unroll
                for (int c = 0; c < CH; ++c) {
                    ku[c] = kv[sj[c] + l];
                    vu[c] = kv[sj[c] + 64 + l];
                }
                #pragma unroll
                for (int c = 0; c < CH; ++c) {
                    float p = bflo(ku[c]) * qlo + bfhi(ku[c]) * qhi;
                    p += __shfl_xor(p, 4, 8);
                    p += __shfl_xor(p, 2, 8);
                    p += __shfl_xor(p, 1, 8);
                    al[c] = p * pr;
                    cmax = fmaxf(cmax, al[c]);
                }
            } else {
                int sj[CH];
                unsigned int ku[CH];
                #pragma unroll
                for (int c = 0; c < CH; ++c) if (c < n) sj[c] = csr_src[base + c];
                #pragma unroll
                for (int c = 0; c < CH; ++c) if (c < n) {
                    ku[c] = kv[sj[c] + l];
                    vu[c] = kv[sj[c] + 64 + l];
                }
                #pragma unroll
                for (int c = 0; c < CH; ++c) if (c < n) {
                    float p = bflo(ku[c]) * qlo + bfhi(ku[c]) * qhi;
                    p += __shfl_xor(p, 4, 8);
                    p += __shfl_xor(p, 2, 8);
                    p += __shfl_xor(p, 1, 8);
                    al[c] = p * pr;
                    cmax = fmaxf(cmax, al[c]);
                }
            }
            float nm = fmaxf(m, cmax);
            float corr = __expf(m - nm);
            den *= corr; alo *= corr; ahi *= corr;
            if (n == CH) {
                #pragma unroll
                for (int c = 0; c < CH; ++c) {
                    float ex = __expf(al[c] - nm);
                    den += ex;
                    alo = fmaf(ex, bflo(vu[c]), alo);
                    ahi = fmaf(ex, bfhi(vu[c]), ahi);
                }
            } else {
                #pragma unroll
                for (int c = 0; c < CH; ++c) if (c < n) {
                    float ex = __expf(al[c] - nm);
                    den += ex;
                    alo = fmaf(ex, bflo(vu[c]), alo);
                    ahi = fmaf(ex, bfhi(vu[c]), ahi);
                }
            }
            m = nm;
        }
        float inv = 1.f / (den + 1e-16f);
        rlo = fmaf(alo, inv, rlo);
        rhi = fmaf(ahi, inv, rhi);
    }
    unsigned int plo = (unsigned int)(unsigned short)f2bf(rlo);
    unsigned int phi = (unsigned int)(unsigned short)f2bf(rhi);
    agg32[(size_t)dst * 64 + l] = plo | (phi << 16);
}

__global__ __launch_bounds__(256) void seg_attn_all(
    const short* __restrict__ qA, const short* __restrict__ kvA0,
    const short* __restrict__ kvA2, const short* __restrict__ qB,
    const short* __restrict__ kvB1,
    const int* __restrict__ off0, const int* __restrict__ off1,
    const int* __restrict__ off2, const int* __restrict__ csrS,
    const float* __restrict__ prelL,
    short* __restrict__ aggA, short* __restrict__ aggB,
    int NA_, int NB_, int nba) {
    if ((int)blockIdx.x < nba) {
        seg_attn_core<2>((const unsigned int*)qA,
                         (const unsigned int*)kvB1, off1,
                         (const unsigned int*)kvA2, off2, csrS,
                         prelL + 1 * NH, prelL + 2 * NH,
                         (unsigned int*)aggA, NA_, blockIdx.x);
    } else {
        seg_attn_core<1>((const unsigned int*)qB,
                         (const unsigned int*)kvA0, off0,
                         nullptr, nullptr, csrS,
                         prelL + 0 * NH, nullptr,
                         (unsigned int*)aggB, NB_, blockIdx.x - nba);
    }
}

extern "C" void kernel_launch(void* const* d_in, const int* in_sizes, int n_in,
                              void* d_out, int out_size, void* d_ws, size_t ws_size,
                              hipStream_t stream) {
    const float* xa   = (const float*)d_in[0];
    const float* xb   = (const float*)d_in[1];
    const int* ei_ab  = (const int*)d_in[2];
    const int* ei_ba  = (const int*)d_in[3];
    const int* ei_aa  = (const int*)d_in[4];
    const float* Wk   = (const float*)d_in[5];
    const float* bk   = (const float*)d_in[6];
    const float* Wq   = (const float*)d_in[7];
    const float* bq   = (const float*)d_in[8];
    const float* Wv   = (const float*)d_in[9];
    const float* bv   = (const float*)d_in[10];
    const float* Wa   = (const float*)d_in[11];
    const float* ba   = (const float*)d_in[12];
    const float* skip = (const float*)d_in[13];
    const float* arel = (const float*)d_in[14];
    const float* mrel = (const float*)d_in[15];
    const float* prel = (const float*)d_in[16];

    const int NA = in_sizes[0] / F;
    const int NB = in_sizes[1] / F;
    const int E0 = in_sizes[2] / 2, E1 = in_sizes[3] / 2, E2 = in_sizes[4] / 2;
    const int ET = E0 + E1 + E2;
    const int NT = NB + NA + NA;   // combined dst space: e0 | e1 | e2

    float* ws = (float*)d_ws;
    size_t o = 0;
    float* bslots = ws + o; o += 2 * 10 * 128;
    // ints
    int* iws = (int*)(ws + o);
    size_t io = 0;
    int* cnt   = iws + io; io += NT;
    int* bsum  = iws + io; io += 1024;
    int* offc  = iws + io; io += NT + 1;
    int* woff  = iws + io; io += NT;
    int* csrS  = iws + io; io += ET;
    io = (io + 7) & ~(size_t)7;
    // shorts (bf16)
    short* sws = (short*)(iws + io);
    size_t so = 0;
    short* qA   = sws + so; so += (size_t)NA * 128;
    short* kvA0 = sws + so; so += (size_t)NA * 256;
    short* kvA2 = sws + so; so += (size_t)NA * 256;
    short* qB   = sws + so; so += (size_t)NB * 128;
    short* kvB1 = sws + so; so += (size_t)NB * 256;
    short* aggA = sws + so; so += (size_t)NA * 128;
    short* aggB = sws + so; so += (size_t)NB * 128;
    short* x1ab = sws + so; so += (size_t)NA * 128;
    short* x1bb = sws + so; so += (size_t)NB * 128;
    short* Wslots = sws + so; so += (size_t)2 * 10 * 16384;

    float* outA = (float*)d_out;
    float* outB = (float*)d_out + (size_t)NA * F;

    // ---- weights for both layers ----
    {
        dim3 g(cdiv(10 * 16384 + 10 * 128, 256), 2);
        prep_weights<<<g, 256, 0, stream>>>(Wk, bk, Wq, bq, Wv, bv, Wa, ba,
                                            arel, mrel, Wslots, bslots);
    }

    // ---- combined CSR ----
    hipMemsetAsync(cnt, 0, (size_t)NT * sizeof(int), stream);
    hist_all<<<cdiv(ET, 256), 256, 0, stream>>>(ei_ab, ei_ba, ei_aa, E0, E1, E2, NB, NA, cnt);
    {
        int nb = cdiv(NT, 256);
        scan1<<<nb, 256, 0, stream>>>(cnt, NT, offc, bsum);
        scan2<<<1, 1024, 0, stream>>>(bsum, nb, offc + NT);
        scan3<<<nb, 256, 0, stream>>>(offc, woff, bsum, NT);
    }
    scatter_all<<<cdiv(ET, 256), 256, 0, stream>>>(ei_ab, ei_ba, ei_aa, E0, E1, E2, NB, NA, woff, csrS);

    const int* off_e0 = offc;
    const int* off_e1 = offc + NB;
    const int* off_e2 = offc + NB + NA;

    const int nbA64 = cdiv(NA, 64), nbB64 = cdiv(NB, 64);
    const int nba4 = cdiv(NA, 4), nbb4 = cdiv(NB, 4);

    for (int l = 0; l < 2; ++l) {
        const short* Wl = Wslots + (size_t)l * 10 * 16384;
        const float* bl = bslots + (size_t)l * 10 * 128;

        if (l == 0) {
            gemm_qkv_all<float><<<nbA64 + nbB64, 256, 0, stream>>>(
                xa, xb, Wl, bl, qA, kvA0, kvA2, qB, kvB1, NA, NB, nbA64);
        } else {
            gemm_qkv_all<short><<<nbA64 + nbB64, 256, 0, stream>>>(
                x1ab, x1bb, Wl, bl, qA, kvA0, kvA2, qB, kvB1, NA, NB, nbA64);
        }

        seg_attn_all<<<nba4 + nbb4, 256, 0, stream>>>(
            qA, kvA0, kvA2, qB, kvB1, off_e0, off_e1, off_e2, csrS,
            prel + (size_t)l * 3 * NH, aggA, aggB, NA, NB, nba4);

        if (l == 0) {
            gemm_out_all<1><<<nbA64 + nbB64, 256, 0, stream>>>(
                aggA, aggB, Wl, bl, xa, xb, nullptr, nullptr,
                skip + 0, nullptr, nullptr, x1ab, x1bb, NA, NB, nbA64);
        } else {
            gemm_out_all<0><<<nbA64 + nbB64, 256, 0, stream>>>(
                aggA, aggB, Wl, bl, nullptr, nullptr, x1ab, x1bb,
                skip + 2, outA, outB, nullptr, nullptr, NA, NB, nbA64);
        }
    }
}